// Round 2
// baseline (1798.725 us; speedup 1.0000x reference)
//
#include <hip/hip_runtime.h>
#include <cstdint>
#include <cstddef>

#define T_DIM   12
#define N_NODES 10000
#define F_DIM   256
#define E_EDGES 160000
#define NSLOT   7     // timesteps 5..11 are the only ones that matter
#define OUT_DIM 64

// ---------------------------------------------------------------------------
// Zero helper (replaces hipMemsetAsync to keep the capture stream pure-kernel)
// ---------------------------------------------------------------------------
__global__ __launch_bounds__(256) void zero_i32_kernel(int* __restrict__ p, int n) {
    int i = blockIdx.x * 256 + threadIdx.x;
    if (i < n) p[i] = 0;
}

// ---------------------------------------------------------------------------
// CSR build: per-timestep incoming-edge lists so A@X is a gather (no atomics
// on feature data).
// ---------------------------------------------------------------------------
__global__ __launch_bounds__(256) void count_kernel(const int* __restrict__ adjs,
                                                    int* __restrict__ counts) {
    int idx = blockIdx.x * 256 + threadIdx.x;
    if (idx >= NSLOT * E_EDGES) return;
    int s = idx / E_EDGES;
    int e = idx - s * E_EDGES;
    int dst = adjs[(size_t)(5 + s) * 2 * E_EDGES + E_EDGES + e];
    atomicAdd(&counts[s * N_NODES + dst], 1);
}

__global__ __launch_bounds__(1024) void scan_kernel(const int* __restrict__ counts,
                                                    int* __restrict__ offsets) {
    int s = blockIdx.x;
    int tid = threadIdx.x;
    __shared__ int sdata[1024];
    __shared__ int srun;
    if (tid == 0) srun = 0;
    __syncthreads();
    const int* c = counts + s * N_NODES;
    int* o = offsets + s * (N_NODES + 1);
    for (int base = 0; base < N_NODES; base += 1024) {
        int v = (base + tid < N_NODES) ? c[base + tid] : 0;
        sdata[tid] = v;
        __syncthreads();
        for (int st = 1; st < 1024; st <<= 1) {
            int x = 0;
            if (tid >= st) x = sdata[tid - st];
            __syncthreads();
            sdata[tid] += x;
            __syncthreads();
        }
        int incl = sdata[tid];
        int run = srun;
        if (base + tid < N_NODES) o[base + tid] = run + incl - v;
        __syncthreads();
        if (tid == 1023) srun = run + sdata[1023];
        __syncthreads();
    }
    if (tid == 0) o[N_NODES] = srun;
}

__global__ __launch_bounds__(256) void fill_kernel(const int* __restrict__ adjs,
                                                   const int* __restrict__ offsets,
                                                   int* __restrict__ cursor,
                                                   int* __restrict__ esrc) {
    int idx = blockIdx.x * 256 + threadIdx.x;
    if (idx >= NSLOT * E_EDGES) return;
    int s = idx / E_EDGES;
    int e = idx - s * E_EDGES;
    const int* a = adjs + (size_t)(5 + s) * 2 * E_EDGES;
    int src = a[e];
    int dst = a[E_EDGES + e];
    int pos = atomicAdd(&cursor[s * N_NODES + dst], 1);
    esrc[(size_t)s * E_EDGES + offsets[s * (N_NODES + 1) + dst] + pos] = src;
}

// ---------------------------------------------------------------------------
// A @ X (segment-sum gather). One block per (slot, dst-node); lane f owns one
// feature. Each edge contributes a coalesced 1KB row read (L2/LLC resident).
// ---------------------------------------------------------------------------
__global__ __launch_bounds__(256) void ax_kernel(const float* __restrict__ xin, int slot_off,
                                                 float* __restrict__ xout,
                                                 const int* __restrict__ offsets,
                                                 const int* __restrict__ esrc) {
    int b = blockIdx.x;
    int s = b / N_NODES;
    int n = b - s * N_NODES;
    int f = threadIdx.x;
    const int* off = offsets + s * (N_NODES + 1);
    int j0 = off[n], j1 = off[n + 1];
    const float* base = xin + (size_t)(slot_off + s) * N_NODES * F_DIM;
    const int* es = esrc + (size_t)s * E_EDGES;
    float acc = 0.f;
    for (int j = j0; j < j1; ++j) {
        int src = es[j];
        acc += base[(size_t)src * F_DIM + f];
    }
    xout[((size_t)s * N_NODES + n) * F_DIM + f] = acc;
}

// ---------------------------------------------------------------------------
// Pre-transpose conv/gate weights: w[l][o][i][k] -> wT[l][k*256+i][o]
// so GEMM B-tiles load coalesced in o.
// ---------------------------------------------------------------------------
__global__ __launch_bounds__(256) void wtrans_kernel(const float* __restrict__ cw,
                                                     const float* __restrict__ gw,
                                                     float* __restrict__ wTc,
                                                     float* __restrict__ wTg) {
    int idx = blockIdx.x * 256 + threadIdx.x;
    if (idx >= 3 * 768 * 256) return;
    int o = idx & 255;
    int rest = idx >> 8;       // l*768 + kidx
    int kidx = rest % 768;
    int l = rest / 768;
    int k = kidx >> 8;
    int i = kidx & 255;
    size_t widx = ((size_t)(l * 256 + o) * 256 + i) * 3 + k;
    wTc[idx] = cw[widx];
    wTg[idx] = gw[widx];
}

// ---------------------------------------------------------------------------
// Gated causal conv as GEMM. Rows = (out-timestep, node), K = 768 (tap,chan),
// cols = 256 out-channels. conv + gate share the A tile (twin accumulators);
// epilogue applies bias and c*sigmoid(g).
//   s_in = s_out + in_slot_base + tap      (slots are t-5)
// ---------------------------------------------------------------------------
#define BM 128
#define BN 64
#define BK 16

__global__ __launch_bounds__(256) void conv_gemm_kernel(
    const float* __restrict__ xin, float* __restrict__ xout,
    const float* __restrict__ wTc, const float* __restrict__ wTg,
    const float* __restrict__ biasc_g, const float* __restrict__ biasg_g,
    int M, int in_slot_base, int out_slot0)
{
    __shared__ float As[BK][BM + 4];    // k-major, stride 132
    __shared__ float Bcs[BK][BN + 4];   // stride 68
    __shared__ float Bgs[BK][BN + 4];

    const int tid = threadIdx.x;
    const int bm = blockIdx.x, bo = blockIdx.y;

    // A-tile load mapping: 2 threads per row, 8 consecutive k each
    const int arow_l = tid >> 1;
    const int arow = bm * BM + arow_l;
    const int acol8 = (tid & 1) * 8;
    int s_out_a = 0, nn = 0;
    const bool arow_ok = arow < M;
    if (arow_ok) { s_out_a = arow / N_NODES; nn = arow - s_out_a * N_NODES; }

    // B-tile load mapping: 16 threads per k-row, float4 each
    const int bi = tid >> 4;
    const int bc4 = (tid & 15) * 4;

    // compute mapping: 8 rows x 4 cols per thread, conv + gate
    const int ty = tid >> 4;   // 0..15
    const int tx = tid & 15;   // 0..15

    float acc_c[8][4] = {};
    float acc_g[8][4] = {};

    for (int kk = 0; kk < 768; kk += BK) {
        const int ktap = kk >> 8;     // uniform within the 16-chunk
        const int c0 = kk & 255;
        float4 a0 = make_float4(0.f, 0.f, 0.f, 0.f);
        float4 a1 = make_float4(0.f, 0.f, 0.f, 0.f);
        if (arow_ok) {
            const float* src = xin +
                ((size_t)(s_out_a + in_slot_base + ktap) * N_NODES + nn) * F_DIM + c0 + acol8;
            a0 = *(const float4*)src;
            a1 = *(const float4*)(src + 4);
        }
        const float* wc = wTc + (size_t)(kk + bi) * 256 + bo * BN + bc4;
        const float* wg = wTg + (size_t)(kk + bi) * 256 + bo * BN + bc4;
        float4 b0 = *(const float4*)wc;
        float4 b1 = *(const float4*)wg;

        __syncthreads();
        As[acol8 + 0][arow_l] = a0.x;
        As[acol8 + 1][arow_l] = a0.y;
        As[acol8 + 2][arow_l] = a0.z;
        As[acol8 + 3][arow_l] = a0.w;
        As[acol8 + 4][arow_l] = a1.x;
        As[acol8 + 5][arow_l] = a1.y;
        As[acol8 + 6][arow_l] = a1.z;
        As[acol8 + 7][arow_l] = a1.w;
        *(float4*)&Bcs[bi][bc4] = b0;
        *(float4*)&Bgs[bi][bc4] = b1;
        __syncthreads();

        #pragma unroll
        for (int k = 0; k < BK; ++k) {
            float4 av0 = *(const float4*)&As[k][ty * 8];
            float4 av1 = *(const float4*)&As[k][ty * 8 + 4];
            float4 vc = *(const float4*)&Bcs[k][tx * 4];
            float4 vg = *(const float4*)&Bgs[k][tx * 4];
            float am[8] = {av0.x, av0.y, av0.z, av0.w, av1.x, av1.y, av1.z, av1.w};
            float vcv[4] = {vc.x, vc.y, vc.z, vc.w};
            float vgv[4] = {vg.x, vg.y, vg.z, vg.w};
            #pragma unroll
            for (int m = 0; m < 8; ++m) {
                #pragma unroll
                for (int j = 0; j < 4; ++j) {
                    acc_c[m][j] += am[m] * vcv[j];
                    acc_g[m][j] += am[m] * vgv[j];
                }
            }
        }
    }

    float4 bcv4 = *(const float4*)(biasc_g + bo * BN + tx * 4);
    float4 bgv4 = *(const float4*)(biasg_g + bo * BN + tx * 4);
    float bcv[4] = {bcv4.x, bcv4.y, bcv4.z, bcv4.w};
    float bgv[4] = {bgv4.x, bgv4.y, bgv4.z, bgv4.w};

    #pragma unroll
    for (int m = 0; m < 8; ++m) {
        int r = bm * BM + ty * 8 + m;
        if (r >= M) continue;
        int so = r / N_NODES;
        int n = r - so * N_NODES;
        float* dst = xout + ((size_t)(out_slot0 + so) * N_NODES + n) * F_DIM + bo * BN + tx * 4;
        float4 o;
        float cv, gv;
        cv = acc_c[m][0] + bcv[0]; gv = acc_g[m][0] + bgv[0];
        o.x = cv * (1.0f / (1.0f + expf(-gv)));
        cv = acc_c[m][1] + bcv[1]; gv = acc_g[m][1] + bgv[1];
        o.y = cv * (1.0f / (1.0f + expf(-gv)));
        cv = acc_c[m][2] + bcv[2]; gv = acc_g[m][2] + bgv[2];
        o.z = cv * (1.0f / (1.0f + expf(-gv)));
        cv = acc_c[m][3] + bcv[3]; gv = acc_g[m][3] + bgv[3];
        o.w = cv * (1.0f / (1.0f + expf(-gv)));
        *(float4*)dst = o;
    }
}

// ---------------------------------------------------------------------------
// Head: out[n] = log_softmax(emb_row @ lin_w.T + lin_b). One wave per node.
// ---------------------------------------------------------------------------
__global__ __launch_bounds__(64) void head_kernel(const float* __restrict__ emb,   // [N][F] (slot 6)
                                                  const float* __restrict__ lin_w, // [64][256]
                                                  const float* __restrict__ lin_b,
                                                  float* __restrict__ out) {
    int n = blockIdx.x;
    int tid = threadIdx.x;   // 0..63 = output channel
    __shared__ float row[F_DIM];
    ((float4*)row)[tid] = ((const float4*)(emb + (size_t)n * F_DIM))[tid];
    __syncthreads();
    float acc = lin_b[tid];
    const float* w = lin_w + (size_t)tid * F_DIM;
    #pragma unroll 8
    for (int c = 0; c < F_DIM; c += 4) {
        float4 wv = *(const float4*)(w + c);
        acc += row[c] * wv.x + row[c + 1] * wv.y + row[c + 2] * wv.z + row[c + 3] * wv.w;
    }
    float mx = acc;
    #pragma unroll
    for (int s = 32; s > 0; s >>= 1) mx = fmaxf(mx, __shfl_xor(mx, s));
    float ex = expf(acc - mx);
    float sum = ex;
    #pragma unroll
    for (int s = 32; s > 0; s >>= 1) sum += __shfl_xor(sum, s);
    out[(size_t)n * OUT_DIM + tid] = acc - mx - logf(sum);
}

// ---------------------------------------------------------------------------
extern "C" void kernel_launch(void* const* d_in, const int* in_sizes, int n_in,
                              void* d_out, int out_size, void* d_ws, size_t ws_size,
                              hipStream_t stream) {
    (void)in_sizes; (void)n_in; (void)out_size; (void)ws_size;
    const float* feats  = (const float*)d_in[0];
    const int*   adjs   = (const int*)d_in[1];
    const float* conv_w = (const float*)d_in[2];
    const float* conv_b = (const float*)d_in[3];
    const float* gate_w = (const float*)d_in[4];
    const float* gate_b = (const float*)d_in[5];
    const float* lin_w  = (const float*)d_in[6];
    const float* lin_b  = (const float*)d_in[7];
    float* out = (float*)d_out;

    char* ws = (char*)d_ws;
    const size_t SX = (size_t)NSLOT * N_NODES * F_DIM * 4;     // 71,680,000 B
    const size_t SW = (size_t)3 * 768 * 256 * 4;               // 2,359,296 B
    const size_t SC = (size_t)NSLOT * N_NODES * 4;             // counts/cursor
    const size_t SO = (((size_t)NSLOT * (N_NODES + 1) * 4) + 255) & ~(size_t)255;

    float* x0      = (float*)ws;
    float* x1      = (float*)(ws + SX);
    float* wTc     = (float*)(ws + 2 * SX);
    float* wTg     = (float*)(ws + 2 * SX + SW);
    int*   counts  = (int*)  (ws + 2 * SX + 2 * SW);
    int*   offsets = (int*)  (ws + 2 * SX + 2 * SW + SC);
    int*   esrc    = (int*)  (ws + 2 * SX + 2 * SW + SC + SO);

    const int ncnt = NSLOT * N_NODES;

    // --- CSR build for slots 0..6 (t = 5..11) ---
    zero_i32_kernel<<<(ncnt + 255) / 256, 256, 0, stream>>>(counts, ncnt);
    const int nedge_thr = NSLOT * E_EDGES;
    count_kernel<<<(nedge_thr + 255) / 256, 256, 0, stream>>>(adjs, counts);
    scan_kernel<<<NSLOT, 1024, 0, stream>>>(counts, offsets);
    zero_i32_kernel<<<(ncnt + 255) / 256, 256, 0, stream>>>(counts, ncnt);  // reuse as cursor
    fill_kernel<<<(nedge_thr + 255) / 256, 256, 0, stream>>>(adjs, offsets, counts, esrc);

    wtrans_kernel<<<(3 * 768 * 256 + 255) / 256, 256, 0, stream>>>(conv_w, gate_w, wTc, wTg);

    // --- graph conv: x0 = A@feats, x1 = A@x0 (same CSR both layers) ---
    ax_kernel<<<NSLOT * N_NODES, 256, 0, stream>>>(feats, 5, x0, offsets, esrc);
    ax_kernel<<<NSLOT * N_NODES, 256, 0, stream>>>(x0, 0, x1, offsets, esrc);

    // --- gated TCN layers (only the timesteps the head can see) ---
    const int M0 = 5 * N_NODES;   // t = 7..11
    conv_gemm_kernel<<<dim3((M0 + BM - 1) / BM, 256 / BN), 256, 0, stream>>>(
        x1, x0, wTc, wTg, conv_b, gate_b, M0, 0, 2);
    const int M1 = 3 * N_NODES;   // t = 9..11
    conv_gemm_kernel<<<dim3((M1 + BM - 1) / BM, 256 / BN), 256, 0, stream>>>(
        x0, x1, wTc + 768 * 256, wTg + 768 * 256, conv_b + 256, gate_b + 256, M1, 2, 4);
    const int M2 = 1 * N_NODES;   // t = 11
    conv_gemm_kernel<<<dim3((M2 + BM - 1) / BM, 256 / BN), 256, 0, stream>>>(
        x1, x0, wTc + 2 * 768 * 256, wTg + 2 * 768 * 256, conv_b + 512, gate_b + 512, M2, 4, 6);

    // --- head: linear + log_softmax on slot 6 ---
    head_kernel<<<N_NODES, 64, 0, stream>>>(x0 + (size_t)6 * N_NODES * F_DIM, lin_w, lin_b, out);
}

// Round 3
// 943.350 us; speedup vs baseline: 1.9067x; 1.9067x over previous
//
#include <hip/hip_runtime.h>
#include <cstdint>
#include <cstddef>

#define T_DIM   12
#define N_NODES 10000
#define F_DIM   256
#define E_EDGES 160000
#define NSLOT   7     // timesteps 5..11 are the only ones that matter
#define OUT_DIM 64
#define CG_BM   128

typedef _Float16 f16;
typedef _Float16 f16x8 __attribute__((ext_vector_type(8)));
typedef _Float16 f16x4 __attribute__((ext_vector_type(4)));
typedef float    f32x4 __attribute__((ext_vector_type(4)));

typedef __attribute__((address_space(1))) const void* as1_cvp;
typedef __attribute__((address_space(3))) void*       as3_vp;

__device__ __forceinline__ void glds16(const void* g, void* l) {
    __builtin_amdgcn_global_load_lds((as1_cvp)g, (as3_vp)l, 16, 0, 0);
}

// ---------------------------------------------------------------------------
// Zero helper (keep capture stream pure-kernel)
// ---------------------------------------------------------------------------
__global__ __launch_bounds__(256) void zero_i32_kernel(int* __restrict__ p, int n) {
    int i = blockIdx.x * 256 + threadIdx.x;
    if (i < n) p[i] = 0;
}

// ---------------------------------------------------------------------------
// CSR build
// ---------------------------------------------------------------------------
__global__ __launch_bounds__(256) void count_kernel(const int* __restrict__ adjs,
                                                    int* __restrict__ counts) {
    int idx = blockIdx.x * 256 + threadIdx.x;
    if (idx >= NSLOT * E_EDGES) return;
    int s = idx / E_EDGES;
    int e = idx - s * E_EDGES;
    int dst = adjs[(size_t)(5 + s) * 2 * E_EDGES + E_EDGES + e];
    atomicAdd(&counts[s * N_NODES + dst], 1);
}

// 2-barrier scan: each thread owns 10 nodes, shfl wave-scan + cross-wave scan.
__global__ __launch_bounds__(1024) void scan_kernel(const int* __restrict__ counts,
                                                    int* __restrict__ offsets) {
    int s = blockIdx.x, tid = threadIdx.x;
    const int* c = counts + s * N_NODES;
    int* o = offsets + s * (N_NODES + 1);
    __shared__ int wsum[16];
    int vals[10];
    int tsum = 0;
    int base = tid * 10;
    #pragma unroll
    for (int j = 0; j < 10; ++j) {
        int i = base + j;
        int v = (i < N_NODES) ? c[i] : 0;
        vals[j] = tsum;          // local exclusive prefix
        tsum += v;
    }
    int lane = tid & 63, wid = tid >> 6;
    int x = tsum;
    #pragma unroll
    for (int d = 1; d < 64; d <<= 1) { int y = __shfl_up(x, d); if (lane >= d) x += y; }
    if (lane == 63) wsum[wid] = x;
    __syncthreads();
    if (wid == 0 && lane < 16) {
        int wv = wsum[lane];
        #pragma unroll
        for (int d = 1; d < 16; d <<= 1) { int y = __shfl_up(wv, d); if (lane >= d) wv += y; }
        wsum[lane] = wv;         // inclusive wave totals
    }
    __syncthreads();
    int waveoff = (wid == 0) ? 0 : wsum[wid - 1];
    int ex = waveoff + (x - tsum);
    #pragma unroll
    for (int j = 0; j < 10; ++j) {
        int i = base + j;
        if (i < N_NODES) o[i] = ex + vals[j];
    }
    if (tid == 1023) o[N_NODES] = wsum[15];
}

__global__ __launch_bounds__(256) void fill_kernel(const int* __restrict__ adjs,
                                                   const int* __restrict__ offsets,
                                                   int* __restrict__ cursor,
                                                   int* __restrict__ esrc) {
    int idx = blockIdx.x * 256 + threadIdx.x;
    if (idx >= NSLOT * E_EDGES) return;
    int s = idx / E_EDGES;
    int e = idx - s * E_EDGES;
    const int* a = adjs + (size_t)(5 + s) * 2 * E_EDGES;
    int src = a[e];
    int dst = a[E_EDGES + e];
    int pos = atomicAdd(&cursor[s * N_NODES + dst], 1);
    esrc[(size_t)s * E_EDGES + offsets[s * (N_NODES + 1) + dst] + pos] = src;
}

// ---------------------------------------------------------------------------
// A @ X gather kernels. Block per (slot,node), lane = feature.
// ---------------------------------------------------------------------------
__global__ __launch_bounds__(256) void ax_kernel(const float* __restrict__ xin, int slot_off,
                                                 float* __restrict__ xout,
                                                 const int* __restrict__ offsets,
                                                 const int* __restrict__ esrc) {
    int b = blockIdx.x;
    int s = b / N_NODES;
    int n = b - s * N_NODES;
    int f = threadIdx.x;
    const int* off = offsets + s * (N_NODES + 1);
    int j0 = off[n], j1 = off[n + 1];
    const float* base = xin + (size_t)(slot_off + s) * N_NODES * F_DIM;
    const int* es = esrc + (size_t)s * E_EDGES;
    float acc = 0.f;
    for (int j = j0; j < j1; ++j) {
        int src = es[j];
        acc += base[(size_t)src * F_DIM + f];
    }
    xout[((size_t)s * N_NODES + n) * F_DIM + f] = acc;
}

// second hop: fp32 gather, fp16 output (conv GEMM A operand)
__global__ __launch_bounds__(256) void ax_f16_kernel(const float* __restrict__ xin,
                                                     f16* __restrict__ xout,
                                                     const int* __restrict__ offsets,
                                                     const int* __restrict__ esrc) {
    int b = blockIdx.x;
    int s = b / N_NODES;
    int n = b - s * N_NODES;
    int f = threadIdx.x;
    const int* off = offsets + s * (N_NODES + 1);
    int j0 = off[n], j1 = off[n + 1];
    const float* base = xin + (size_t)s * N_NODES * F_DIM;
    const int* es = esrc + (size_t)s * E_EDGES;
    float acc = 0.f;
    for (int j = j0; j < j1; ++j) {
        int src = es[j];
        acc += base[(size_t)src * F_DIM + f];
    }
    xout[((size_t)s * N_NODES + n) * F_DIM + f] = (f16)acc;
}

// ---------------------------------------------------------------------------
// Weight pack: w[l][o][i][tap] (fp32) -> wTt fp16 [l][bo(4)][kk(24)][cg(2)][col(64)][k(32)]
// so each (l,bo,kk) B-block is a contiguous 8KB staged by linear global_load_lds.
// ---------------------------------------------------------------------------
__global__ __launch_bounds__(256) void wtrans16_kernel(const float* __restrict__ cw,
                                                       const float* __restrict__ gw,
                                                       f16* __restrict__ wTt) {
    int idx = blockIdx.x * 256 + threadIdx.x;
    if (idx >= 3 * 4 * 24 * 2 * 64 * 32) return;
    int k   = idx & 31;
    int col = (idx >> 5) & 63;
    int cg  = (idx >> 11) & 1;
    int r   = idx >> 12;            // (l*4 + bo)*24 + kk
    int lbo = r / 24;
    int kk  = r - lbo * 24;
    int l   = lbo >> 2, bo = lbo & 3;
    int K   = kk * 32 + k;
    int tap = K >> 8;
    int ci  = K & 255;
    int o   = bo * 64 + col;
    const float* src = cg ? gw : cw;
    wTt[idx] = (f16)src[(((size_t)l * 256 + o) * 256 + ci) * 3 + tap];
}

// ---------------------------------------------------------------------------
// Gated causal conv as fp16 MFMA GEMM (fp32 accumulate).
// Block: 256 thr = 4 waves; tile 128 rows x 64 cols, twin (conv+gate) B.
// Wave (wr,wc): 64x32 twin sub-tile = 4 row-frags x 2 col-frags x 2 tensors
// = 16 x mfma_f32_16x16x32_f16 per BK=32 step; K = 768 = 24 steps.
// LDS: A [128 rows][32 k] fp16 (8KB) + B^T [cg][64 col][32 k] (8KB), linear,
// staged with global_load_lds width=16. 64B row stride => bank-uniform reads.
// ---------------------------------------------------------------------------
__global__ __launch_bounds__(256) void conv_gemm_f16_kernel(
    const f16* __restrict__ xin, f16* __restrict__ xout,
    const f16* __restrict__ wTt,           // this layer's [4][24][2][64][32]
    const float* __restrict__ biasc, const float* __restrict__ biasg,
    int M, int in_slot_base, int out_slot0)
{
    __shared__ __align__(16) f16 lds[8192];   // A: [0,4096), B: [4096,8192) halves

    const int tid = threadIdx.x;
    const int ln  = tid & 63;
    const int w   = __builtin_amdgcn_readfirstlane(tid >> 6);
    const int bm  = blockIdx.x, bo = blockIdx.y;
    const int wr  = w >> 1, wc = w & 1;

    // ---- staging address precompute (per lane) ----
    const size_t SLOTB = (size_t)N_NODES * F_DIM * 2;   // bytes per slot
    const char* xin_b = (const char*)xin + (size_t)in_slot_base * SLOTB;
    int r0  = 32 * w + (ln >> 2);
    int gr0 = bm * CG_BM + r0;      if (gr0 > M - 1) gr0 = M - 1;
    int gr1 = bm * CG_BM + r0 + 16; if (gr1 > M - 1) gr1 = M - 1;
    int sg0 = gr0 / N_NODES, nn0 = gr0 - sg0 * N_NODES;
    int sg1 = gr1 / N_NODES, nn1 = gr1 - sg1 * N_NODES;
    const char* aptr0 = xin_b + (size_t)sg0 * SLOTB + (size_t)nn0 * 512 + (ln & 3) * 16;
    const char* aptr1 = xin_b + (size_t)sg1 * SLOTB + (size_t)nn1 * 512 + (ln & 3) * 16;
    const char* bptr  = (const char*)wTt + (size_t)bo * (24 * 8192)
                        + (size_t)(2 * w) * 1024 + (size_t)ln * 16;

    f16* ldsA0 = &lds[(2 * w    ) * 512];
    f16* ldsA1 = &lds[(2 * w + 1) * 512];
    f16* ldsB0 = &lds[4096 + (2 * w    ) * 512];
    f16* ldsB1 = &lds[4096 + (2 * w + 1) * 512];

    // fragment read offsets (half-index); 64B row stride -> bank-uniform
    const int aoff = (wr * 64 + (ln & 15)) * 32 + (ln >> 4) * 8;
    const int boff = 4096 + (wc * 32 + (ln & 15)) * 32 + (ln >> 4) * 8;

    f32x4 acc_c[4][2] = {};
    f32x4 acc_g[4][2] = {};

    for (int kk = 0; kk < 24; ++kk) {
        const size_t aoffb = (size_t)(kk >> 3) * SLOTB + (size_t)(kk & 7) * 64;
        const char* gb = bptr + (size_t)kk * 8192;
        glds16(aptr0 + aoffb, ldsA0);
        glds16(aptr1 + aoffb, ldsA1);
        glds16(gb,        ldsB0);
        glds16(gb + 1024, ldsB1);
        __syncthreads();   // drains vmcnt -> staged tile visible

        f16x8 af0 = *(const f16x8*)&lds[aoff];
        f16x8 af1 = *(const f16x8*)&lds[aoff + 512];
        f16x8 af2 = *(const f16x8*)&lds[aoff + 1024];
        f16x8 af3 = *(const f16x8*)&lds[aoff + 1536];
        f16x8 bc0 = *(const f16x8*)&lds[boff];
        f16x8 bc1 = *(const f16x8*)&lds[boff + 512];
        f16x8 bg0 = *(const f16x8*)&lds[boff + 2048];
        f16x8 bg1 = *(const f16x8*)&lds[boff + 2560];

        acc_c[0][0] = __builtin_amdgcn_mfma_f32_16x16x32_f16(af0, bc0, acc_c[0][0], 0, 0, 0);
        acc_g[0][0] = __builtin_amdgcn_mfma_f32_16x16x32_f16(af0, bg0, acc_g[0][0], 0, 0, 0);
        acc_c[0][1] = __builtin_amdgcn_mfma_f32_16x16x32_f16(af0, bc1, acc_c[0][1], 0, 0, 0);
        acc_g[0][1] = __builtin_amdgcn_mfma_f32_16x16x32_f16(af0, bg1, acc_g[0][1], 0, 0, 0);
        acc_c[1][0] = __builtin_amdgcn_mfma_f32_16x16x32_f16(af1, bc0, acc_c[1][0], 0, 0, 0);
        acc_g[1][0] = __builtin_amdgcn_mfma_f32_16x16x32_f16(af1, bg0, acc_g[1][0], 0, 0, 0);
        acc_c[1][1] = __builtin_amdgcn_mfma_f32_16x16x32_f16(af1, bc1, acc_c[1][1], 0, 0, 0);
        acc_g[1][1] = __builtin_amdgcn_mfma_f32_16x16x32_f16(af1, bg1, acc_g[1][1], 0, 0, 0);
        acc_c[2][0] = __builtin_amdgcn_mfma_f32_16x16x32_f16(af2, bc0, acc_c[2][0], 0, 0, 0);
        acc_g[2][0] = __builtin_amdgcn_mfma_f32_16x16x32_f16(af2, bg0, acc_g[2][0], 0, 0, 0);
        acc_c[2][1] = __builtin_amdgcn_mfma_f32_16x16x32_f16(af2, bc1, acc_c[2][1], 0, 0, 0);
        acc_g[2][1] = __builtin_amdgcn_mfma_f32_16x16x32_f16(af2, bg1, acc_g[2][1], 0, 0, 0);
        acc_c[3][0] = __builtin_amdgcn_mfma_f32_16x16x32_f16(af3, bc0, acc_c[3][0], 0, 0, 0);
        acc_g[3][0] = __builtin_amdgcn_mfma_f32_16x16x32_f16(af3, bg0, acc_g[3][0], 0, 0, 0);
        acc_c[3][1] = __builtin_amdgcn_mfma_f32_16x16x32_f16(af3, bc1, acc_c[3][1], 0, 0, 0);
        acc_g[3][1] = __builtin_amdgcn_mfma_f32_16x16x32_f16(af3, bg1, acc_g[3][1], 0, 0, 0);

        __syncthreads();   // all frag reads done before next stage overwrites
    }

    // epilogue: D layout col = lane&15, row = (lane>>4)*4 + reg  [m89-verified]
    #pragma unroll
    for (int rb = 0; rb < 4; ++rb) {
        int grow0 = bm * CG_BM + wr * 64 + rb * 16 + ((ln >> 4) << 2);
        #pragma unroll
        for (int cf = 0; cf < 2; ++cf) {
            int gcol = bo * 64 + wc * 32 + cf * 16 + (ln & 15);
            float bc = biasc[gcol], bg = biasg[gcol];
            #pragma unroll
            for (int r = 0; r < 4; ++r) {
                int grow = grow0 + r;
                if (grow < M) {
                    int sg = grow / N_NODES;
                    int nn = grow - sg * N_NODES;
                    float cv = acc_c[rb][cf][r] + bc;
                    float gv = acc_g[rb][cf][r] + bg;
                    float y  = cv / (1.0f + expf(-gv));
                    xout[((size_t)(out_slot0 + sg) * N_NODES + nn) * F_DIM + gcol] = (f16)y;
                }
            }
        }
    }
}

// ---------------------------------------------------------------------------
// Head: out[n] = log_softmax(emb_row(fp16) @ lin_w.T + lin_b). One wave/node.
// ---------------------------------------------------------------------------
__global__ __launch_bounds__(64) void head_kernel(const f16* __restrict__ emb,    // [N][F] slot 6
                                                  const float* __restrict__ lin_w, // [64][256]
                                                  const float* __restrict__ lin_b,
                                                  float* __restrict__ out) {
    int n = blockIdx.x;
    int tid = threadIdx.x;   // 0..63 = output channel
    __shared__ float row[F_DIM];
    f16x4 hv = *(const f16x4*)(emb + (size_t)n * F_DIM + tid * 4);
    row[tid * 4 + 0] = (float)hv[0];
    row[tid * 4 + 1] = (float)hv[1];
    row[tid * 4 + 2] = (float)hv[2];
    row[tid * 4 + 3] = (float)hv[3];
    __syncthreads();
    float acc = lin_b[tid];
    const float* w = lin_w + (size_t)tid * F_DIM;
    #pragma unroll 8
    for (int c = 0; c < F_DIM; c += 4) {
        float4 wv = *(const float4*)(w + c);
        acc += row[c] * wv.x + row[c + 1] * wv.y + row[c + 2] * wv.z + row[c + 3] * wv.w;
    }
    float mx = acc;
    #pragma unroll
    for (int s = 32; s > 0; s >>= 1) mx = fmaxf(mx, __shfl_xor(mx, s));
    float ex = expf(acc - mx);
    float sum = ex;
    #pragma unroll
    for (int s = 32; s > 0; s >>= 1) sum += __shfl_xor(sum, s);
    out[(size_t)n * OUT_DIM + tid] = acc - mx - logf(sum);
}

// ---------------------------------------------------------------------------
extern "C" void kernel_launch(void* const* d_in, const int* in_sizes, int n_in,
                              void* d_out, int out_size, void* d_ws, size_t ws_size,
                              hipStream_t stream) {
    (void)in_sizes; (void)n_in; (void)out_size; (void)ws_size;
    const float* feats  = (const float*)d_in[0];
    const int*   adjs   = (const int*)d_in[1];
    const float* conv_w = (const float*)d_in[2];
    const float* conv_b = (const float*)d_in[3];
    const float* gate_w = (const float*)d_in[4];
    const float* gate_b = (const float*)d_in[5];
    const float* lin_w  = (const float*)d_in[6];
    const float* lin_b  = (const float*)d_in[7];
    float* out = (float*)d_out;

    char* ws = (char*)d_ws;
    const size_t OX0  = 0;                    // x0 fp32: 71,680,000 B
    const size_t OXA  = OX0 + 71680000;       // x16a:    35,840,000 B
    const size_t OXB  = OXA + 35840000;       // x16b:    35,840,000 B
    const size_t OWT  = OXB + 35840000;       // wTt:      2,359,296 B
    const size_t OCN  = OWT + 2359296;        // counts:     280,000 B
    const size_t OOF  = OCN + 280000;         // offsets:    280,064 B (padded)
    const size_t OES  = OOF + 280064;         // esrc:     4,480,000 B

    float* x0      = (float*)(ws + OX0);
    f16*   x16a    = (f16*)  (ws + OXA);
    f16*   x16b    = (f16*)  (ws + OXB);
    f16*   wTt     = (f16*)  (ws + OWT);
    int*   counts  = (int*)  (ws + OCN);
    int*   offsets = (int*)  (ws + OOF);
    int*   esrc    = (int*)  (ws + OES);

    const int ncnt = NSLOT * N_NODES;
    const int nedge_thr = NSLOT * E_EDGES;
    const int LWT = 4 * 24 * 2 * 64 * 32;     // halves per layer in wTt

    // --- CSR build for slots 0..6 (t = 5..11) ---
    zero_i32_kernel<<<(ncnt + 255) / 256, 256, 0, stream>>>(counts, ncnt);
    count_kernel<<<(nedge_thr + 255) / 256, 256, 0, stream>>>(adjs, counts);
    scan_kernel<<<NSLOT, 1024, 0, stream>>>(counts, offsets);
    zero_i32_kernel<<<(ncnt + 255) / 256, 256, 0, stream>>>(counts, ncnt);  // reuse as cursor
    fill_kernel<<<(nedge_thr + 255) / 256, 256, 0, stream>>>(adjs, offsets, counts, esrc);

    wtrans16_kernel<<<(3 * LWT + 255) / 256, 256, 0, stream>>>(conv_w, gate_w, wTt);

    // --- graph conv: x0 = A@feats (fp32), x16a = A@x0 (fp16 out) ---
    ax_kernel<<<NSLOT * N_NODES, 256, 0, stream>>>(feats, 5, x0, offsets, esrc);
    ax_f16_kernel<<<NSLOT * N_NODES, 256, 0, stream>>>(x0, x16a, offsets, esrc);

    // --- gated TCN layers (fp16 MFMA GEMMs) ---
    const int M0 = 5 * N_NODES;   // out slots 2..6, reads 0..6
    conv_gemm_f16_kernel<<<dim3((M0 + CG_BM - 1) / CG_BM, 4), 256, 0, stream>>>(
        x16a, x16b, wTt, conv_b, gate_b, M0, 0, 2);
    const int M1 = 3 * N_NODES;   // out slots 4..6, reads 2..6
    conv_gemm_f16_kernel<<<dim3((M1 + CG_BM - 1) / CG_BM, 4), 256, 0, stream>>>(
        x16b, x16a, wTt + LWT, conv_b + 256, gate_b + 256, M1, 2, 4);
    const int M2 = 1 * N_NODES;   // out slot 6, reads 4..6
    conv_gemm_f16_kernel<<<dim3((M2 + CG_BM - 1) / CG_BM, 4), 256, 0, stream>>>(
        x16a, x16b, wTt + 2 * LWT, conv_b + 512, gate_b + 512, M2, 4, 6);

    // --- head: linear + log_softmax on slot 6 ---
    head_kernel<<<N_NODES, 64, 0, stream>>>(x16b + (size_t)6 * N_NODES * F_DIM, lin_w, lin_b, out);
}

// Round 5
// 729.287 us; speedup vs baseline: 2.4664x; 1.2935x over previous
//
#include <hip/hip_runtime.h>
#include <cstdint>
#include <cstddef>

#define T_DIM   12
#define N_NODES 10000
#define F_DIM   256
#define E_EDGES 160000
#define NSLOT   7     // timesteps 5..11 are the only ones that matter
#define OUT_DIM 64
#define CG_BM   128

typedef _Float16 f16;
typedef _Float16 f16x8 __attribute__((ext_vector_type(8)));
typedef _Float16 f16x4 __attribute__((ext_vector_type(4)));
typedef float    f32x4 __attribute__((ext_vector_type(4)));

typedef __attribute__((address_space(1))) const void* as1_cvp;
typedef __attribute__((address_space(3))) void*       as3_vp;

__device__ __forceinline__ void glds16(const void* g, void* l) {
    __builtin_amdgcn_global_load_lds((as1_cvp)g, (as3_vp)l, 16, 0, 0);
}

// ---------------------------------------------------------------------------
// Zero helper (keep capture stream pure-kernel)
// ---------------------------------------------------------------------------
__global__ __launch_bounds__(256) void zero_i32_kernel(int* __restrict__ p, int n) {
    int i = blockIdx.x * 256 + threadIdx.x;
    if (i < n) p[i] = 0;
}

// ---------------------------------------------------------------------------
// CSR build
// ---------------------------------------------------------------------------
__global__ __launch_bounds__(256) void count_kernel(const int* __restrict__ adjs,
                                                    int* __restrict__ counts) {
    int idx = blockIdx.x * 256 + threadIdx.x;
    if (idx >= NSLOT * E_EDGES) return;
    int s = idx / E_EDGES;
    int e = idx - s * E_EDGES;
    int dst = adjs[(size_t)(5 + s) * 2 * E_EDGES + E_EDGES + e];
    atomicAdd(&counts[s * N_NODES + dst], 1);
}

// 2-barrier scan: each thread owns 10 nodes, shfl wave-scan + cross-wave scan.
__global__ __launch_bounds__(1024) void scan_kernel(const int* __restrict__ counts,
                                                    int* __restrict__ offsets) {
    int s = blockIdx.x, tid = threadIdx.x;
    const int* c = counts + s * N_NODES;
    int* o = offsets + s * (N_NODES + 1);
    __shared__ int wsum[16];
    int vals[10];
    int tsum = 0;
    int base = tid * 10;
    #pragma unroll
    for (int j = 0; j < 10; ++j) {
        int i = base + j;
        int v = (i < N_NODES) ? c[i] : 0;
        vals[j] = tsum;          // local exclusive prefix
        tsum += v;
    }
    int lane = tid & 63, wid = tid >> 6;
    int x = tsum;
    #pragma unroll
    for (int d = 1; d < 64; d <<= 1) { int y = __shfl_up(x, d); if (lane >= d) x += y; }
    if (lane == 63) wsum[wid] = x;
    __syncthreads();
    if (wid == 0 && lane < 16) {
        int wv = wsum[lane];
        #pragma unroll
        for (int d = 1; d < 16; d <<= 1) { int y = __shfl_up(wv, d); if (lane >= d) wv += y; }
        wsum[lane] = wv;         // inclusive wave totals
    }
    __syncthreads();
    int waveoff = (wid == 0) ? 0 : wsum[wid - 1];
    int ex = waveoff + (x - tsum);
    #pragma unroll
    for (int j = 0; j < 10; ++j) {
        int i = base + j;
        if (i < N_NODES) o[i] = ex + vals[j];
    }
    if (tid == 1023) o[N_NODES] = wsum[15];
}

__global__ __launch_bounds__(256) void fill_kernel(const int* __restrict__ adjs,
                                                   const int* __restrict__ offsets,
                                                   int* __restrict__ cursor,
                                                   int* __restrict__ esrc) {
    int idx = blockIdx.x * 256 + threadIdx.x;
    if (idx >= NSLOT * E_EDGES) return;
    int s = idx / E_EDGES;
    int e = idx - s * E_EDGES;
    const int* a = adjs + (size_t)(5 + s) * 2 * E_EDGES;
    int src = a[e];
    int dst = a[E_EDGES + e];
    int pos = atomicAdd(&cursor[s * N_NODES + dst], 1);
    esrc[(size_t)s * E_EDGES + offsets[s * (N_NODES + 1) + dst] + pos] = src;
}

// ---------------------------------------------------------------------------
// A @ X gather: ONE WAVE per (slot,node); lane owns 4 contiguous floats
// (float4 = 16B/lane, 1KB per row-load instruction). Edge loop unrolled x8 so
// 8 independent row loads are in flight per wave (128B/lane outstanding).
// ---------------------------------------------------------------------------
__global__ __launch_bounds__(256) void ax_kernel(const float* __restrict__ xin, int slot_off,
                                                 float* __restrict__ xout,
                                                 const int* __restrict__ offsets,
                                                 const int* __restrict__ esrc) {
    int wv = (blockIdx.x << 2) + (threadIdx.x >> 6);
    if (wv >= NSLOT * N_NODES) return;
    int s = wv / N_NODES;
    int n = wv - s * N_NODES;
    int lane = threadIdx.x & 63;
    const int* off = offsets + s * (N_NODES + 1);
    int j0 = off[n], j1 = off[n + 1];
    const float* base = xin + (size_t)(slot_off + s) * N_NODES * F_DIM + lane * 4;
    const int* es = esrc + (size_t)s * E_EDGES;
    float ax = 0.f, ay = 0.f, az = 0.f, aw = 0.f;
    int j = j0;
    for (; j + 8 <= j1; j += 8) {
        int i0 = es[j], i1 = es[j+1], i2 = es[j+2], i3 = es[j+3];
        int i4 = es[j+4], i5 = es[j+5], i6 = es[j+6], i7 = es[j+7];
        float4 r0 = *(const float4*)(base + (size_t)i0 * F_DIM);
        float4 r1 = *(const float4*)(base + (size_t)i1 * F_DIM);
        float4 r2 = *(const float4*)(base + (size_t)i2 * F_DIM);
        float4 r3 = *(const float4*)(base + (size_t)i3 * F_DIM);
        float4 r4 = *(const float4*)(base + (size_t)i4 * F_DIM);
        float4 r5 = *(const float4*)(base + (size_t)i5 * F_DIM);
        float4 r6 = *(const float4*)(base + (size_t)i6 * F_DIM);
        float4 r7 = *(const float4*)(base + (size_t)i7 * F_DIM);
        ax += ((r0.x + r1.x) + (r2.x + r3.x)) + ((r4.x + r5.x) + (r6.x + r7.x));
        ay += ((r0.y + r1.y) + (r2.y + r3.y)) + ((r4.y + r5.y) + (r6.y + r7.y));
        az += ((r0.z + r1.z) + (r2.z + r3.z)) + ((r4.z + r5.z) + (r6.z + r7.z));
        aw += ((r0.w + r1.w) + (r2.w + r3.w)) + ((r4.w + r5.w) + (r6.w + r7.w));
    }
    for (; j < j1; ++j) {
        float4 r = *(const float4*)(base + (size_t)es[j] * F_DIM);
        ax += r.x; ay += r.y; az += r.z; aw += r.w;
    }
    *(float4*)(xout + ((size_t)s * N_NODES + n) * F_DIM + lane * 4) =
        make_float4(ax, ay, az, aw);
}

// second hop: fp32 gather, fp16 output (conv GEMM A operand)
__global__ __launch_bounds__(256) void ax_f16_kernel(const float* __restrict__ xin,
                                                     f16* __restrict__ xout,
                                                     const int* __restrict__ offsets,
                                                     const int* __restrict__ esrc) {
    int wv = (blockIdx.x << 2) + (threadIdx.x >> 6);
    if (wv >= NSLOT * N_NODES) return;
    int s = wv / N_NODES;
    int n = wv - s * N_NODES;
    int lane = threadIdx.x & 63;
    const int* off = offsets + s * (N_NODES + 1);
    int j0 = off[n], j1 = off[n + 1];
    const float* base = xin + (size_t)s * N_NODES * F_DIM + lane * 4;
    const int* es = esrc + (size_t)s * E_EDGES;
    float ax = 0.f, ay = 0.f, az = 0.f, aw = 0.f;
    int j = j0;
    for (; j + 8 <= j1; j += 8) {
        int i0 = es[j], i1 = es[j+1], i2 = es[j+2], i3 = es[j+3];
        int i4 = es[j+4], i5 = es[j+5], i6 = es[j+6], i7 = es[j+7];
        float4 r0 = *(const float4*)(base + (size_t)i0 * F_DIM);
        float4 r1 = *(const float4*)(base + (size_t)i1 * F_DIM);
        float4 r2 = *(const float4*)(base + (size_t)i2 * F_DIM);
        float4 r3 = *(const float4*)(base + (size_t)i3 * F_DIM);
        float4 r4 = *(const float4*)(base + (size_t)i4 * F_DIM);
        float4 r5 = *(const float4*)(base + (size_t)i5 * F_DIM);
        float4 r6 = *(const float4*)(base + (size_t)i6 * F_DIM);
        float4 r7 = *(const float4*)(base + (size_t)i7 * F_DIM);
        ax += ((r0.x + r1.x) + (r2.x + r3.x)) + ((r4.x + r5.x) + (r6.x + r7.x));
        ay += ((r0.y + r1.y) + (r2.y + r3.y)) + ((r4.y + r5.y) + (r6.y + r7.y));
        az += ((r0.z + r1.z) + (r2.z + r3.z)) + ((r4.z + r5.z) + (r6.z + r7.z));
        aw += ((r0.w + r1.w) + (r2.w + r3.w)) + ((r4.w + r5.w) + (r6.w + r7.w));
    }
    for (; j < j1; ++j) {
        float4 r = *(const float4*)(base + (size_t)es[j] * F_DIM);
        ax += r.x; ay += r.y; az += r.z; aw += r.w;
    }
    f16x4 o;
    o[0] = (f16)ax; o[1] = (f16)ay; o[2] = (f16)az; o[3] = (f16)aw;
    *(f16x4*)(xout + ((size_t)s * N_NODES + n) * F_DIM + lane * 4) = o;
}

// ---------------------------------------------------------------------------
// Weight pack: w[l][o][i][tap] (fp32) -> wTt fp16 [l][bo(4)][kk(24)][cg(2)][col(64)][k(32)]
// so each (l,bo,kk) B-block is a contiguous 8KB staged by linear global_load_lds.
// ---------------------------------------------------------------------------
__global__ __launch_bounds__(256) void wtrans16_kernel(const float* __restrict__ cw,
                                                       const float* __restrict__ gw,
                                                       f16* __restrict__ wTt) {
    int idx = blockIdx.x * 256 + threadIdx.x;
    if (idx >= 3 * 4 * 24 * 2 * 64 * 32) return;
    int k   = idx & 31;
    int col = (idx >> 5) & 63;
    int cg  = (idx >> 11) & 1;
    int r   = idx >> 12;            // (l*4 + bo)*24 + kk
    int lbo = r / 24;
    int kk  = r - lbo * 24;
    int l   = lbo >> 2, bo = lbo & 3;
    int K   = kk * 32 + k;
    int tap = K >> 8;
    int ci  = K & 255;
    int o   = bo * 64 + col;
    const float* src = cg ? gw : cw;
    wTt[idx] = (f16)src[(((size_t)l * 256 + o) * 256 + ci) * 3 + tap];
}

// ---------------------------------------------------------------------------
// Gated causal conv as fp16 MFMA GEMM (fp32 accumulate).
// Block: 256 thr = 4 waves; tile 128 rows x 64 cols, twin (conv+gate) B.
// Wave (wr,wc): 64x32 twin sub-tile = 4 row-frags x 2 col-frags x 2 tensors
// = 16 x mfma_f32_16x16x32_f16 per BK=32 step; K = 768 = 24 steps.
// LDS: A [128 rows][32 k] fp16 (8KB) + B^T [cg][64 col][32 k] (8KB), linear,
// staged with global_load_lds width=16. 64B row stride => bank-uniform reads.
// ---------------------------------------------------------------------------
__global__ __launch_bounds__(256) void conv_gemm_f16_kernel(
    const f16* __restrict__ xin, f16* __restrict__ xout,
    const f16* __restrict__ wTt,           // this layer's [4][24][2][64][32]
    const float* __restrict__ biasc, const float* __restrict__ biasg,
    int M, int in_slot_base, int out_slot0)
{
    __shared__ __align__(16) f16 lds[8192];   // A: [0,4096), B: [4096,8192) halves

    const int tid = threadIdx.x;
    const int ln  = tid & 63;
    const int w   = __builtin_amdgcn_readfirstlane(tid >> 6);
    const int bm  = blockIdx.x, bo = blockIdx.y;
    const int wr  = w >> 1, wc = w & 1;

    // ---- staging address precompute (per lane) ----
    const size_t SLOTB = (size_t)N_NODES * F_DIM * 2;   // bytes per slot
    const char* xin_b = (const char*)xin + (size_t)in_slot_base * SLOTB;
    int r0  = 32 * w + (ln >> 2);
    int gr0 = bm * CG_BM + r0;      if (gr0 > M - 1) gr0 = M - 1;
    int gr1 = bm * CG_BM + r0 + 16; if (gr1 > M - 1) gr1 = M - 1;
    int sg0 = gr0 / N_NODES, nn0 = gr0 - sg0 * N_NODES;
    int sg1 = gr1 / N_NODES, nn1 = gr1 - sg1 * N_NODES;
    const char* aptr0 = xin_b + (size_t)sg0 * SLOTB + (size_t)nn0 * 512 + (ln & 3) * 16;
    const char* aptr1 = xin_b + (size_t)sg1 * SLOTB + (size_t)nn1 * 512 + (ln & 3) * 16;
    const char* bptr  = (const char*)wTt + (size_t)bo * (24 * 8192)
                        + (size_t)(2 * w) * 1024 + (size_t)ln * 16;

    f16* ldsA0 = &lds[(2 * w    ) * 512];
    f16* ldsA1 = &lds[(2 * w + 1) * 512];
    f16* ldsB0 = &lds[4096 + (2 * w    ) * 512];
    f16* ldsB1 = &lds[4096 + (2 * w + 1) * 512];

    // fragment read offsets (half-index); 64B row stride -> bank-uniform
    const int aoff = (wr * 64 + (ln & 15)) * 32 + (ln >> 4) * 8;
    const int boff = 4096 + (wc * 32 + (ln & 15)) * 32 + (ln >> 4) * 8;

    f32x4 acc_c[4][2] = {};
    f32x4 acc_g[4][2] = {};

    for (int kk = 0; kk < 24; ++kk) {
        const size_t aoffb = (size_t)(kk >> 3) * SLOTB + (size_t)(kk & 7) * 64;
        const char* gb = bptr + (size_t)kk * 8192;
        glds16(aptr0 + aoffb, ldsA0);
        glds16(aptr1 + aoffb, ldsA1);
        glds16(gb,        ldsB0);
        glds16(gb + 1024, ldsB1);
        __syncthreads();   // drains vmcnt -> staged tile visible

        f16x8 af0 = *(const f16x8*)&lds[aoff];
        f16x8 af1 = *(const f16x8*)&lds[aoff + 512];
        f16x8 af2 = *(const f16x8*)&lds[aoff + 1024];
        f16x8 af3 = *(const f16x8*)&lds[aoff + 1536];
        f16x8 bc0 = *(const f16x8*)&lds[boff];
        f16x8 bc1 = *(const f16x8*)&lds[boff + 512];
        f16x8 bg0 = *(const f16x8*)&lds[boff + 2048];
        f16x8 bg1 = *(const f16x8*)&lds[boff + 2560];

        acc_c[0][0] = __builtin_amdgcn_mfma_f32_16x16x32_f16(af0, bc0, acc_c[0][0], 0, 0, 0);
        acc_g[0][0] = __builtin_amdgcn_mfma_f32_16x16x32_f16(af0, bg0, acc_g[0][0], 0, 0, 0);
        acc_c[0][1] = __builtin_amdgcn_mfma_f32_16x16x32_f16(af0, bc1, acc_c[0][1], 0, 0, 0);
        acc_g[0][1] = __builtin_amdgcn_mfma_f32_16x16x32_f16(af0, bg1, acc_g[0][1], 0, 0, 0);
        acc_c[1][0] = __builtin_amdgcn_mfma_f32_16x16x32_f16(af1, bc0, acc_c[1][0], 0, 0, 0);
        acc_g[1][0] = __builtin_amdgcn_mfma_f32_16x16x32_f16(af1, bg0, acc_g[1][0], 0, 0, 0);
        acc_c[1][1] = __builtin_amdgcn_mfma_f32_16x16x32_f16(af1, bc1, acc_c[1][1], 0, 0, 0);
        acc_g[1][1] = __builtin_amdgcn_mfma_f32_16x16x32_f16(af1, bg1, acc_g[1][1], 0, 0, 0);
        acc_c[2][0] = __builtin_amdgcn_mfma_f32_16x16x32_f16(af2, bc0, acc_c[2][0], 0, 0, 0);
        acc_g[2][0] = __builtin_amdgcn_mfma_f32_16x16x32_f16(af2, bg0, acc_g[2][0], 0, 0, 0);
        acc_c[2][1] = __builtin_amdgcn_mfma_f32_16x16x32_f16(af2, bc1, acc_c[2][1], 0, 0, 0);
        acc_g[2][1] = __builtin_amdgcn_mfma_f32_16x16x32_f16(af2, bg1, acc_g[2][1], 0, 0, 0);
        acc_c[3][0] = __builtin_amdgcn_mfma_f32_16x16x32_f16(af3, bc0, acc_c[3][0], 0, 0, 0);
        acc_g[3][0] = __builtin_amdgcn_mfma_f32_16x16x32_f16(af3, bg0, acc_g[3][0], 0, 0, 0);
        acc_c[3][1] = __builtin_amdgcn_mfma_f32_16x16x32_f16(af3, bc1, acc_c[3][1], 0, 0, 0);
        acc_g[3][1] = __builtin_amdgcn_mfma_f32_16x16x32_f16(af3, bg1, acc_g[3][1], 0, 0, 0);

        __syncthreads();   // all frag reads done before next stage overwrites
    }

    // epilogue: D layout col = lane&15, row = (lane>>4)*4 + reg  [m89-verified]
    #pragma unroll
    for (int rb = 0; rb < 4; ++rb) {
        int grow0 = bm * CG_BM + wr * 64 + rb * 16 + ((ln >> 4) << 2);
        #pragma unroll
        for (int cf = 0; cf < 2; ++cf) {
            int gcol = bo * 64 + wc * 32 + cf * 16 + (ln & 15);
            float bc = biasc[gcol], bg = biasg[gcol];
            #pragma unroll
            for (int r = 0; r < 4; ++r) {
                int grow = grow0 + r;
                if (grow < M) {
                    int sg = grow / N_NODES;
                    int nn = grow - sg * N_NODES;
                    float cv = acc_c[rb][cf][r] + bc;
                    float gv = acc_g[rb][cf][r] + bg;
                    float y  = cv / (1.0f + expf(-gv));
                    xout[((size_t)(out_slot0 + sg) * N_NODES + nn) * F_DIM + gcol] = (f16)y;
                }
            }
        }
    }
}

// ---------------------------------------------------------------------------
// Head: out[n] = log_softmax(emb_row(fp16) @ lin_w.T + lin_b). One wave/node.
// ---------------------------------------------------------------------------
__global__ __launch_bounds__(64) void head_kernel(const f16* __restrict__ emb,    // [N][F] slot 6
                                                  const float* __restrict__ lin_w, // [64][256]
                                                  const float* __restrict__ lin_b,
                                                  float* __restrict__ out) {
    int n = blockIdx.x;
    int tid = threadIdx.x;   // 0..63 = output channel
    __shared__ float row[F_DIM];
    f16x4 hv = *(const f16x4*)(emb + (size_t)n * F_DIM + tid * 4);
    row[tid * 4 + 0] = (float)hv[0];
    row[tid * 4 + 1] = (float)hv[1];
    row[tid * 4 + 2] = (float)hv[2];
    row[tid * 4 + 3] = (float)hv[3];
    __syncthreads();
    float acc = lin_b[tid];
    const float* w = lin_w + (size_t)tid * F_DIM;
    #pragma unroll 8
    for (int c = 0; c < F_DIM; c += 4) {
        float4 wv = *(const float4*)(w + c);
        acc += row[c] * wv.x + row[c + 1] * wv.y + row[c + 2] * wv.z + row[c + 3] * wv.w;
    }
    float mx = acc;
    #pragma unroll
    for (int s = 32; s > 0; s >>= 1) mx = fmaxf(mx, __shfl_xor(mx, s));
    float ex = expf(acc - mx);
    float sum = ex;
    #pragma unroll
    for (int s = 32; s > 0; s >>= 1) sum += __shfl_xor(sum, s);
    out[(size_t)n * OUT_DIM + tid] = acc - mx - logf(sum);
}

// ---------------------------------------------------------------------------
extern "C" void kernel_launch(void* const* d_in, const int* in_sizes, int n_in,
                              void* d_out, int out_size, void* d_ws, size_t ws_size,
                              hipStream_t stream) {
    (void)in_sizes; (void)n_in; (void)out_size; (void)ws_size;
    const float* feats  = (const float*)d_in[0];
    const int*   adjs   = (const int*)d_in[1];
    const float* conv_w = (const float*)d_in[2];
    const float* conv_b = (const float*)d_in[3];
    const float* gate_w = (const float*)d_in[4];
    const float* gate_b = (const float*)d_in[5];
    const float* lin_w  = (const float*)d_in[6];
    const float* lin_b  = (const float*)d_in[7];
    float* out = (float*)d_out;

    char* ws = (char*)d_ws;
    const size_t OX0  = 0;                    // x0 fp32: 71,680,000 B
    const size_t OXA  = OX0 + 71680000;       // x16a:    35,840,000 B
    const size_t OXB  = OXA + 35840000;       // x16b:    35,840,000 B
    const size_t OWT  = OXB + 35840000;       // wTt:      2,359,296 B
    const size_t OCN  = OWT + 2359296;        // counts:     280,000 B
    const size_t OOF  = OCN + 280000;         // offsets:    280,064 B (padded)
    const size_t OES  = OOF + 280064;         // esrc:     4,480,000 B

    float* x0      = (float*)(ws + OX0);
    f16*   x16a    = (f16*)  (ws + OXA);
    f16*   x16b    = (f16*)  (ws + OXB);
    f16*   wTt     = (f16*)  (ws + OWT);
    int*   counts  = (int*)  (ws + OCN);
    int*   offsets = (int*)  (ws + OOF);
    int*   esrc    = (int*)  (ws + OES);

    const int ncnt = NSLOT * N_NODES;
    const int nedge_thr = NSLOT * E_EDGES;
    const int LWT = 4 * 24 * 2 * 64 * 32;     // halves per layer in wTt
    const int nwave = NSLOT * N_NODES;        // one wave per (slot,node)

    // --- CSR build for slots 0..6 (t = 5..11) ---
    zero_i32_kernel<<<(ncnt + 255) / 256, 256, 0, stream>>>(counts, ncnt);
    count_kernel<<<(nedge_thr + 255) / 256, 256, 0, stream>>>(adjs, counts);
    scan_kernel<<<NSLOT, 1024, 0, stream>>>(counts, offsets);
    zero_i32_kernel<<<(ncnt + 255) / 256, 256, 0, stream>>>(counts, ncnt);  // reuse as cursor
    fill_kernel<<<(nedge_thr + 255) / 256, 256, 0, stream>>>(adjs, offsets, counts, esrc);

    wtrans16_kernel<<<(3 * LWT + 255) / 256, 256, 0, stream>>>(conv_w, gate_w, wTt);

    // --- graph conv: x0 = A@feats (fp32), x16a = A@x0 (fp16 out) ---
    ax_kernel<<<(nwave + 3) / 4, 256, 0, stream>>>(feats, 5, x0, offsets, esrc);
    ax_f16_kernel<<<(nwave + 3) / 4, 256, 0, stream>>>(x0, x16a, offsets, esrc);

    // --- gated TCN layers (fp16 MFMA GEMMs) ---
    const int M0 = 5 * N_NODES;   // out slots 2..6, reads 0..6
    conv_gemm_f16_kernel<<<dim3((M0 + CG_BM - 1) / CG_BM, 4), 256, 0, stream>>>(
        x16a, x16b, wTt, conv_b, gate_b, M0, 0, 2);
    const int M1 = 3 * N_NODES;   // out slots 4..6, reads 2..6
    conv_gemm_f16_kernel<<<dim3((M1 + CG_BM - 1) / CG_BM, 4), 256, 0, stream>>>(
        x16b, x16a, wTt + LWT, conv_b + 256, gate_b + 256, M1, 2, 4);
    const int M2 = 1 * N_NODES;   // out slot 6, reads 4..6
    conv_gemm_f16_kernel<<<dim3((M2 + CG_BM - 1) / CG_BM, 4), 256, 0, stream>>>(
        x16a, x16b, wTt + 2 * LWT, conv_b + 512, gate_b + 512, M2, 4, 6);

    // --- head: linear + log_softmax on slot 6 ---
    head_kernel<<<N_NODES, 64, 0, stream>>>(x16b + (size_t)6 * N_NODES * F_DIM, lin_w, lin_b, out);
}

// Round 7
// 659.628 us; speedup vs baseline: 2.7269x; 1.1056x over previous
//
#include <hip/hip_runtime.h>
#include <cstdint>
#include <cstddef>

#define T_DIM   12
#define N_NODES 10000
#define F_DIM   256
#define E_EDGES 160000
#define NSLOT   7     // timesteps 5..11 are the only ones that matter
#define OUT_DIM 64
#define CG_BM   128

typedef _Float16 f16;
typedef _Float16 f16x8 __attribute__((ext_vector_type(8)));
typedef _Float16 f16x4 __attribute__((ext_vector_type(4)));
typedef float    f32x4 __attribute__((ext_vector_type(4)));

typedef __attribute__((address_space(1))) const void* as1_cvp;
typedef __attribute__((address_space(3))) void*       as3_vp;

__device__ __forceinline__ void glds16(const void* g, void* l) {
    __builtin_amdgcn_global_load_lds((as1_cvp)g, (as3_vp)l, 16, 0, 0);
}

// ---------------------------------------------------------------------------
// Zero helper (keep capture stream pure-kernel)
// ---------------------------------------------------------------------------
__global__ __launch_bounds__(256) void zero_i32_kernel(int* __restrict__ p, int n) {
    int i = blockIdx.x * 256 + threadIdx.x;
    if (i < n) p[i] = 0;
}

// ---------------------------------------------------------------------------
// feats (fp32, slots 5..11) -> fp16, streaming. 8 floats per thread.
// ---------------------------------------------------------------------------
__global__ __launch_bounds__(256) void feats2f16_kernel(const float* __restrict__ feats,
                                                        f16* __restrict__ xout) {
    int idx = blockIdx.x * 256 + threadIdx.x;   // 8 floats each
    const int total = NSLOT * N_NODES * F_DIM;  // 17,920,000
    int i0 = idx * 8;
    if (i0 >= total) return;
    const float* src = feats + (size_t)5 * N_NODES * F_DIM + i0;
    float4 a = *(const float4*)src;
    float4 b = *(const float4*)(src + 4);
    f16x8 o;
    o[0] = (f16)a.x; o[1] = (f16)a.y; o[2] = (f16)a.z; o[3] = (f16)a.w;
    o[4] = (f16)b.x; o[5] = (f16)b.y; o[6] = (f16)b.z; o[7] = (f16)b.w;
    *(f16x8*)(xout + i0) = o;
}

// ---------------------------------------------------------------------------
// CSR build
// ---------------------------------------------------------------------------
__global__ __launch_bounds__(256) void count_kernel(const int* __restrict__ adjs,
                                                    int* __restrict__ counts) {
    int idx = blockIdx.x * 256 + threadIdx.x;
    if (idx >= NSLOT * E_EDGES) return;
    int s = idx / E_EDGES;
    int e = idx - s * E_EDGES;
    int dst = adjs[(size_t)(5 + s) * 2 * E_EDGES + E_EDGES + e];
    atomicAdd(&counts[s * N_NODES + dst], 1);
}

// 2-barrier scan: each thread owns 10 nodes, shfl wave-scan + cross-wave scan.
__global__ __launch_bounds__(1024) void scan_kernel(const int* __restrict__ counts,
                                                    int* __restrict__ offsets) {
    int s = blockIdx.x, tid = threadIdx.x;
    const int* c = counts + s * N_NODES;
    int* o = offsets + s * (N_NODES + 1);
    __shared__ int wsum[16];
    int vals[10];
    int tsum = 0;
    int base = tid * 10;
    #pragma unroll
    for (int j = 0; j < 10; ++j) {
        int i = base + j;
        int v = (i < N_NODES) ? c[i] : 0;
        vals[j] = tsum;          // local exclusive prefix
        tsum += v;
    }
    int lane = tid & 63, wid = tid >> 6;
    int x = tsum;
    #pragma unroll
    for (int d = 1; d < 64; d <<= 1) { int y = __shfl_up(x, d); if (lane >= d) x += y; }
    if (lane == 63) wsum[wid] = x;
    __syncthreads();
    if (wid == 0 && lane < 16) {
        int wv = wsum[lane];
        #pragma unroll
        for (int d = 1; d < 16; d <<= 1) { int y = __shfl_up(wv, d); if (lane >= d) wv += y; }
        wsum[lane] = wv;         // inclusive wave totals
    }
    __syncthreads();
    int waveoff = (wid == 0) ? 0 : wsum[wid - 1];
    int ex = waveoff + (x - tsum);
    #pragma unroll
    for (int j = 0; j < 10; ++j) {
        int i = base + j;
        if (i < N_NODES) o[i] = ex + vals[j];
    }
    if (tid == 1023) o[N_NODES] = wsum[15];
}

__global__ __launch_bounds__(256) void fill_kernel(const int* __restrict__ adjs,
                                                   const int* __restrict__ offsets,
                                                   int* __restrict__ cursor,
                                                   int* __restrict__ esrc) {
    int idx = blockIdx.x * 256 + threadIdx.x;
    if (idx >= NSLOT * E_EDGES) return;
    int s = idx / E_EDGES;
    int e = idx - s * E_EDGES;
    const int* a = adjs + (size_t)(5 + s) * 2 * E_EDGES;
    int src = a[e];
    int dst = a[E_EDGES + e];
    int pos = atomicAdd(&cursor[s * N_NODES + dst], 1);
    esrc[(size_t)s * E_EDGES + offsets[s * (N_NODES + 1) + dst] + pos] = src;
}

// ---------------------------------------------------------------------------
// A @ X gather, fp16 rows, slot->XCD affinity.
// Grid = 8 * 2500 blocks; XCD = blockIdx & 7 (empirical round-robin), slot =
// XCD (XCD 7 idles). Confines each slot's 5.12MB source set to one XCD's L2.
// One wave per node; lane owns 4 halves (8B); edge loop unrolled x8.
// fp32 accumulate, fp16 out.
// ---------------------------------------------------------------------------
__global__ __launch_bounds__(256) void ax16_kernel(const f16* __restrict__ xin,
                                                   f16* __restrict__ xout,
                                                   const int* __restrict__ offsets,
                                                   const int* __restrict__ esrc) {
    int s = blockIdx.x & 7;
    if (s >= NSLOT) return;
    int n = ((blockIdx.x >> 3) << 2) + (threadIdx.x >> 6);
    int lane = threadIdx.x & 63;
    const int* off = offsets + s * (N_NODES + 1);
    int j0 = off[n], j1 = off[n + 1];
    const f16* base = xin + (size_t)s * N_NODES * F_DIM + lane * 4;
    const int* es = esrc + (size_t)s * E_EDGES;
    float ax = 0.f, ay = 0.f, az = 0.f, aw = 0.f;
    int j = j0;
    for (; j + 8 <= j1; j += 8) {
        int i0 = es[j], i1 = es[j+1], i2 = es[j+2], i3 = es[j+3];
        int i4 = es[j+4], i5 = es[j+5], i6 = es[j+6], i7 = es[j+7];
        f16x4 r0 = *(const f16x4*)(base + (size_t)i0 * F_DIM);
        f16x4 r1 = *(const f16x4*)(base + (size_t)i1 * F_DIM);
        f16x4 r2 = *(const f16x4*)(base + (size_t)i2 * F_DIM);
        f16x4 r3 = *(const f16x4*)(base + (size_t)i3 * F_DIM);
        f16x4 r4 = *(const f16x4*)(base + (size_t)i4 * F_DIM);
        f16x4 r5 = *(const f16x4*)(base + (size_t)i5 * F_DIM);
        f16x4 r6 = *(const f16x4*)(base + (size_t)i6 * F_DIM);
        f16x4 r7 = *(const f16x4*)(base + (size_t)i7 * F_DIM);
        ax += (((float)r0[0] + (float)r1[0]) + ((float)r2[0] + (float)r3[0]))
            + (((float)r4[0] + (float)r5[0]) + ((float)r6[0] + (float)r7[0]));
        ay += (((float)r0[1] + (float)r1[1]) + ((float)r2[1] + (float)r3[1]))
            + (((float)r4[1] + (float)r5[1]) + ((float)r6[1] + (float)r7[1]));
        az += (((float)r0[2] + (float)r1[2]) + ((float)r2[2] + (float)r3[2]))
            + (((float)r4[2] + (float)r5[2]) + ((float)r6[2] + (float)r7[2]));
        aw += (((float)r0[3] + (float)r1[3]) + ((float)r2[3] + (float)r3[3]))
            + (((float)r4[3] + (float)r5[3]) + ((float)r6[3] + (float)r7[3]));
    }
    for (; j < j1; ++j) {
        f16x4 r = *(const f16x4*)(base + (size_t)es[j] * F_DIM);
        ax += (float)r[0]; ay += (float)r[1]; az += (float)r[2]; aw += (float)r[3];
    }
    f16x4 o;
    o[0] = (f16)ax; o[1] = (f16)ay; o[2] = (f16)az; o[3] = (f16)aw;
    *(f16x4*)(xout + ((size_t)s * N_NODES + n) * F_DIM + lane * 4) = o;
}

// ---------------------------------------------------------------------------
// Weight pack: w[l][o][i][tap] (fp32) -> wTt fp16 [l][bo(4)][kk(24)][cg(2)][col(64)][k(32)]
// so each (l,bo,kk) B-block is a contiguous 8KB staged by linear global_load_lds.
// ---------------------------------------------------------------------------
__global__ __launch_bounds__(256) void wtrans16_kernel(const float* __restrict__ cw,
                                                       const float* __restrict__ gw,
                                                       f16* __restrict__ wTt) {
    int idx = blockIdx.x * 256 + threadIdx.x;
    if (idx >= 3 * 4 * 24 * 2 * 64 * 32) return;
    int k   = idx & 31;
    int col = (idx >> 5) & 63;
    int cg  = (idx >> 11) & 1;
    int r   = idx >> 12;            // (l*4 + bo)*24 + kk
    int lbo = r / 24;
    int kk  = r - lbo * 24;
    int l   = lbo >> 2, bo = lbo & 3;
    int K   = kk * 32 + k;
    int tap = K >> 8;
    int ci  = K & 255;
    int o   = bo * 64 + col;
    const float* src = cg ? gw : cw;
    wTt[idx] = (f16)src[(((size_t)l * 256 + o) * 256 + ci) * 3 + tap];
}

// ---------------------------------------------------------------------------
// Gated causal conv as fp16 MFMA GEMM (fp32 accumulate).
// Block: 256 thr = 4 waves; tile 128 rows x 64 cols, twin (conv+gate) B.
// Wave (wr,wc): 64x32 twin sub-tile = 4 row-frags x 2 col-frags x 2 tensors
// = 16 x mfma_f32_16x16x32_f16 per BK=32 step; K = 768 = 24 steps.
// LDS: A [128 rows][32 k] fp16 (8KB) + B^T [cg][64 col][32 k] (8KB), linear,
// staged with global_load_lds width=16. 64B row stride => bank-uniform reads.
// ---------------------------------------------------------------------------
__global__ __launch_bounds__(256) void conv_gemm_f16_kernel(
    const f16* __restrict__ xin, f16* __restrict__ xout,
    const f16* __restrict__ wTt,           // this layer's [4][24][2][64][32]
    const float* __restrict__ biasc, const float* __restrict__ biasg,
    int M, int in_slot_base, int out_slot0)
{
    __shared__ __align__(16) f16 lds[8192];   // A: [0,4096), B: [4096,8192) halves

    const int tid = threadIdx.x;
    const int ln  = tid & 63;
    const int w   = __builtin_amdgcn_readfirstlane(tid >> 6);
    const int bm  = blockIdx.x, bo = blockIdx.y;
    const int wr  = w >> 1, wc = w & 1;

    // ---- staging address precompute (per lane) ----
    const size_t SLOTB = (size_t)N_NODES * F_DIM * 2;   // bytes per slot
    const char* xin_b = (const char*)xin + (size_t)in_slot_base * SLOTB;
    int r0  = 32 * w + (ln >> 2);
    int gr0 = bm * CG_BM + r0;      if (gr0 > M - 1) gr0 = M - 1;
    int gr1 = bm * CG_BM + r0 + 16; if (gr1 > M - 1) gr1 = M - 1;
    int sg0 = gr0 / N_NODES, nn0 = gr0 - sg0 * N_NODES;
    int sg1 = gr1 / N_NODES, nn1 = gr1 - sg1 * N_NODES;
    const char* aptr0 = xin_b + (size_t)sg0 * SLOTB + (size_t)nn0 * 512 + (ln & 3) * 16;
    const char* aptr1 = xin_b + (size_t)sg1 * SLOTB + (size_t)nn1 * 512 + (ln & 3) * 16;
    const char* bptr  = (const char*)wTt + (size_t)bo * (24 * 8192)
                        + (size_t)(2 * w) * 1024 + (size_t)ln * 16;

    f16* ldsA0 = &lds[(2 * w    ) * 512];
    f16* ldsA1 = &lds[(2 * w + 1) * 512];
    f16* ldsB0 = &lds[4096 + (2 * w    ) * 512];
    f16* ldsB1 = &lds[4096 + (2 * w + 1) * 512];

    // fragment read offsets (half-index); 64B row stride -> bank-uniform
    const int aoff = (wr * 64 + (ln & 15)) * 32 + (ln >> 4) * 8;
    const int boff = 4096 + (wc * 32 + (ln & 15)) * 32 + (ln >> 4) * 8;

    f32x4 acc_c[4][2] = {};
    f32x4 acc_g[4][2] = {};

    for (int kk = 0; kk < 24; ++kk) {
        const size_t aoffb = (size_t)(kk >> 3) * SLOTB + (size_t)(kk & 7) * 64;
        const char* gb = bptr + (size_t)kk * 8192;
        glds16(aptr0 + aoffb, ldsA0);
        glds16(aptr1 + aoffb, ldsA1);
        glds16(gb,        ldsB0);
        glds16(gb + 1024, ldsB1);
        __syncthreads();   // drains vmcnt -> staged tile visible

        f16x8 af0 = *(const f16x8*)&lds[aoff];
        f16x8 af1 = *(const f16x8*)&lds[aoff + 512];
        f16x8 af2 = *(const f16x8*)&lds[aoff + 1024];
        f16x8 af3 = *(const f16x8*)&lds[aoff + 1536];
        f16x8 bc0 = *(const f16x8*)&lds[boff];
        f16x8 bc1 = *(const f16x8*)&lds[boff + 512];
        f16x8 bg0 = *(const f16x8*)&lds[boff + 2048];
        f16x8 bg1 = *(const f16x8*)&lds[boff + 2560];

        acc_c[0][0] = __builtin_amdgcn_mfma_f32_16x16x32_f16(af0, bc0, acc_c[0][0], 0, 0, 0);
        acc_g[0][0] = __builtin_amdgcn_mfma_f32_16x16x32_f16(af0, bg0, acc_g[0][0], 0, 0, 0);
        acc_c[0][1] = __builtin_amdgcn_mfma_f32_16x16x32_f16(af0, bc1, acc_c[0][1], 0, 0, 0);
        acc_g[0][1] = __builtin_amdgcn_mfma_f32_16x16x32_f16(af0, bg1, acc_g[0][1], 0, 0, 0);
        acc_c[1][0] = __builtin_amdgcn_mfma_f32_16x16x32_f16(af1, bc0, acc_c[1][0], 0, 0, 0);
        acc_g[1][0] = __builtin_amdgcn_mfma_f32_16x16x32_f16(af1, bg0, acc_g[1][0], 0, 0, 0);
        acc_c[1][1] = __builtin_amdgcn_mfma_f32_16x16x32_f16(af1, bc1, acc_c[1][1], 0, 0, 0);
        acc_g[1][1] = __builtin_amdgcn_mfma_f32_16x16x32_f16(af1, bg1, acc_g[1][1], 0, 0, 0);
        acc_c[2][0] = __builtin_amdgcn_mfma_f32_16x16x32_f16(af2, bc0, acc_c[2][0], 0, 0, 0);
        acc_g[2][0] = __builtin_amdgcn_mfma_f32_16x16x32_f16(af2, bg0, acc_g[2][0], 0, 0, 0);
        acc_c[2][1] = __builtin_amdgcn_mfma_f32_16x16x32_f16(af2, bc1, acc_c[2][1], 0, 0, 0);
        acc_g[2][1] = __builtin_amdgcn_mfma_f32_16x16x32_f16(af2, bg1, acc_g[2][1], 0, 0, 0);
        acc_c[3][0] = __builtin_amdgcn_mfma_f32_16x16x32_f16(af3, bc0, acc_c[3][0], 0, 0, 0);
        acc_g[3][0] = __builtin_amdgcn_mfma_f32_16x16x32_f16(af3, bg0, acc_g[3][0], 0, 0, 0);
        acc_c[3][1] = __builtin_amdgcn_mfma_f32_16x16x32_f16(af3, bc1, acc_c[3][1], 0, 0, 0);
        acc_g[3][1] = __builtin_amdgcn_mfma_f32_16x16x32_f16(af3, bg1, acc_g[3][1], 0, 0, 0);

        __syncthreads();   // all frag reads done before next stage overwrites
    }

    // epilogue: D layout col = lane&15, row = (lane>>4)*4 + reg  [m89-verified]
    #pragma unroll
    for (int rb = 0; rb < 4; ++rb) {
        int grow0 = bm * CG_BM + wr * 64 + rb * 16 + ((ln >> 4) << 2);
        #pragma unroll
        for (int cf = 0; cf < 2; ++cf) {
            int gcol = bo * 64 + wc * 32 + cf * 16 + (ln & 15);
            float bc = biasc[gcol], bg = biasg[gcol];
            #pragma unroll
            for (int r = 0; r < 4; ++r) {
                int grow = grow0 + r;
                if (grow < M) {
                    int sg = grow / N_NODES;
                    int nn = grow - sg * N_NODES;
                    float cv = acc_c[rb][cf][r] + bc;
                    float gv = acc_g[rb][cf][r] + bg;
                    float y  = cv / (1.0f + expf(-gv));
                    xout[((size_t)(out_slot0 + sg) * N_NODES + nn) * F_DIM + gcol] = (f16)y;
                }
            }
        }
    }
}

// ---------------------------------------------------------------------------
// Head: out[n] = log_softmax(emb_row(fp16) @ lin_w.T + lin_b). One wave/node.
// ---------------------------------------------------------------------------
__global__ __launch_bounds__(64) void head_kernel(const f16* __restrict__ emb,    // [N][F] slot 6
                                                  const float* __restrict__ lin_w, // [64][256]
                                                  const float* __restrict__ lin_b,
                                                  float* __restrict__ out) {
    int n = blockIdx.x;
    int tid = threadIdx.x;   // 0..63 = output channel
    __shared__ float row[F_DIM];
    f16x4 hv = *(const f16x4*)(emb + (size_t)n * F_DIM + tid * 4);
    row[tid * 4 + 0] = (float)hv[0];
    row[tid * 4 + 1] = (float)hv[1];
    row[tid * 4 + 2] = (float)hv[2];
    row[tid * 4 + 3] = (float)hv[3];
    __syncthreads();
    float acc = lin_b[tid];
    const float* w = lin_w + (size_t)tid * F_DIM;
    #pragma unroll 8
    for (int c = 0; c < F_DIM; c += 4) {
        float4 wv = *(const float4*)(w + c);
        acc += row[c] * wv.x + row[c + 1] * wv.y + row[c + 2] * wv.z + row[c + 3] * wv.w;
    }
    float mx = acc;
    #pragma unroll
    for (int s = 32; s > 0; s >>= 1) mx = fmaxf(mx, __shfl_xor(mx, s));
    float ex = expf(acc - mx);
    float sum = ex;
    #pragma unroll
    for (int s = 32; s > 0; s >>= 1) sum += __shfl_xor(sum, s);
    out[(size_t)n * OUT_DIM + tid] = acc - mx - logf(sum);
}

// ---------------------------------------------------------------------------
extern "C" void kernel_launch(void* const* d_in, const int* in_sizes, int n_in,
                              void* d_out, int out_size, void* d_ws, size_t ws_size,
                              hipStream_t stream) {
    (void)in_sizes; (void)n_in; (void)out_size; (void)ws_size;
    const float* feats  = (const float*)d_in[0];
    const int*   adjs   = (const int*)d_in[1];
    const float* conv_w = (const float*)d_in[2];
    const float* conv_b = (const float*)d_in[3];
    const float* gate_w = (const float*)d_in[4];
    const float* gate_b = (const float*)d_in[5];
    const float* lin_w  = (const float*)d_in[6];
    const float* lin_b  = (const float*)d_in[7];
    float* out = (float*)d_out;

    char* ws = (char*)d_ws;
    const size_t SX16 = (size_t)NSLOT * N_NODES * F_DIM * 2;  // 35,840,000 B
    const size_t OXF  = 0;                    // x16f (feats fp16)
    const size_t OXP  = OXF + SX16;           // x16p (hop1 out)
    const size_t OXA  = OXP + SX16;           // x16a (hop2 out / conv ping)
    const size_t OXB  = OXA + SX16;           // x16b (conv pong)
    const size_t OWT  = OXB + SX16;           // wTt:      2,359,296 B
    const size_t OCN  = OWT + 2359296;        // counts:     280,000 B
    const size_t OOF  = OCN + 280000;         // offsets:    280,064 B (padded)
    const size_t OES  = OOF + 280064;         // esrc:     4,480,000 B

    f16*   x16f    = (f16*)  (ws + OXF);
    f16*   x16p    = (f16*)  (ws + OXP);
    f16*   x16a    = (f16*)  (ws + OXA);
    f16*   x16b    = (f16*)  (ws + OXB);
    f16*   wTt     = (f16*)  (ws + OWT);
    int*   counts  = (int*)  (ws + OCN);
    int*   offsets = (int*)  (ws + OOF);
    int*   esrc    = (int*)  (ws + OES);

    const int ncnt = NSLOT * N_NODES;
    const int nedge_thr = NSLOT * E_EDGES;
    const int LWT = 4 * 24 * 2 * 64 * 32;     // halves per layer in wTt
    const int nconv8 = NSLOT * N_NODES * F_DIM / 8;  // convert threads

    // --- CSR build for slots 0..6 (t = 5..11) ---
    zero_i32_kernel<<<(ncnt + 255) / 256, 256, 0, stream>>>(counts, ncnt);
    count_kernel<<<(nedge_thr + 255) / 256, 256, 0, stream>>>(adjs, counts);
    scan_kernel<<<NSLOT, 1024, 0, stream>>>(counts, offsets);
    zero_i32_kernel<<<(ncnt + 255) / 256, 256, 0, stream>>>(counts, ncnt);  // reuse as cursor
    fill_kernel<<<(nedge_thr + 255) / 256, 256, 0, stream>>>(adjs, offsets, counts, esrc);

    wtrans16_kernel<<<(3 * LWT + 255) / 256, 256, 0, stream>>>(conv_w, gate_w, wTt);
    feats2f16_kernel<<<(nconv8 + 255) / 256, 256, 0, stream>>>(feats, x16f);

    // --- graph conv, fp16 gathers with slot->XCD affinity (8*2500 blocks) ---
    ax16_kernel<<<8 * (N_NODES / 4), 256, 0, stream>>>(x16f, x16p, offsets, esrc);
    ax16_kernel<<<8 * (N_NODES / 4), 256, 0, stream>>>(x16p, x16a, offsets, esrc);

    // --- gated TCN layers (fp16 MFMA GEMMs) ---
    const int M0 = 5 * N_NODES;   // out slots 2..6, reads 0..6
    conv_gemm_f16_kernel<<<dim3((M0 + CG_BM - 1) / CG_BM, 4), 256, 0, stream>>>(
        x16a, x16b, wTt, conv_b, gate_b, M0, 0, 2);
    const int M1 = 3 * N_NODES;   // out slots 4..6, reads 2..6
    conv_gemm_f16_kernel<<<dim3((M1 + CG_BM - 1) / CG_BM, 4), 256, 0, stream>>>(
        x16b, x16a, wTt + LWT, conv_b + 256, gate_b + 256, M1, 2, 4);
    const int M2 = 1 * N_NODES;   // out slot 6, reads 4..6
    conv_gemm_f16_kernel<<<dim3((M2 + CG_BM - 1) / CG_BM, 4), 256, 0, stream>>>(
        x16a, x16b, wTt + 2 * LWT, conv_b + 512, gate_b + 512, M2, 4, 6);

    // --- head: linear + log_softmax on slot 6 ---
    head_kernel<<<N_NODES, 64, 0, stream>>>(x16b + (size_t)6 * N_NODES * F_DIM, lin_w, lin_b, out);
}

// Round 8
// 628.105 us; speedup vs baseline: 2.8637x; 1.0502x over previous
//
#include <hip/hip_runtime.h>
#include <cstdint>
#include <cstddef>

#define T_DIM   12
#define N_NODES 10000
#define F_DIM   256
#define E_EDGES 160000
#define NSLOT   7     // timesteps 5..11 are the only ones that matter
#define OUT_DIM 64
#define CG_BM   128

typedef _Float16 f16;
typedef _Float16 f16x8 __attribute__((ext_vector_type(8)));
typedef _Float16 f16x4 __attribute__((ext_vector_type(4)));
typedef float    f32x4 __attribute__((ext_vector_type(4)));

typedef __attribute__((address_space(1))) const void* as1_cvp;
typedef __attribute__((address_space(3))) void*       as3_vp;

__device__ __forceinline__ void glds16(const void* g, void* l) {
    __builtin_amdgcn_global_load_lds((as1_cvp)g, (as3_vp)l, 16, 0, 0);
}

// ---------------------------------------------------------------------------
// Zero helper (keep capture stream pure-kernel)
// ---------------------------------------------------------------------------
__global__ __launch_bounds__(256) void zero_i32_kernel(int* __restrict__ p, int n) {
    int i = blockIdx.x * 256 + threadIdx.x;
    if (i < n) p[i] = 0;
}

// ---------------------------------------------------------------------------
// feats (fp32, slots 5..11) -> fp16, streaming. 8 floats per thread.
// ---------------------------------------------------------------------------
__global__ __launch_bounds__(256) void feats2f16_kernel(const float* __restrict__ feats,
                                                        f16* __restrict__ xout) {
    int idx = blockIdx.x * 256 + threadIdx.x;   // 8 floats each
    const int total = NSLOT * N_NODES * F_DIM;  // 17,920,000
    int i0 = idx * 8;
    if (i0 >= total) return;
    const float* src = feats + (size_t)5 * N_NODES * F_DIM + i0;
    float4 a = *(const float4*)src;
    float4 b = *(const float4*)(src + 4);
    f16x8 o;
    o[0] = (f16)a.x; o[1] = (f16)a.y; o[2] = (f16)a.z; o[3] = (f16)a.w;
    o[4] = (f16)b.x; o[5] = (f16)b.y; o[6] = (f16)b.z; o[7] = (f16)b.w;
    *(f16x8*)(xout + i0) = o;
}

// ---------------------------------------------------------------------------
// CSR build
// ---------------------------------------------------------------------------
__global__ __launch_bounds__(256) void count_kernel(const int* __restrict__ adjs,
                                                    int* __restrict__ counts) {
    int idx = blockIdx.x * 256 + threadIdx.x;
    if (idx >= NSLOT * E_EDGES) return;
    int s = idx / E_EDGES;
    int e = idx - s * E_EDGES;
    int dst = adjs[(size_t)(5 + s) * 2 * E_EDGES + E_EDGES + e];
    atomicAdd(&counts[s * N_NODES + dst], 1);
}

// 2-barrier scan: each thread owns 10 nodes, shfl wave-scan + cross-wave scan.
__global__ __launch_bounds__(1024) void scan_kernel(const int* __restrict__ counts,
                                                    int* __restrict__ offsets) {
    int s = blockIdx.x, tid = threadIdx.x;
    const int* c = counts + s * N_NODES;
    int* o = offsets + s * (N_NODES + 1);
    __shared__ int wsum[16];
    int vals[10];
    int tsum = 0;
    int base = tid * 10;
    #pragma unroll
    for (int j = 0; j < 10; ++j) {
        int i = base + j;
        int v = (i < N_NODES) ? c[i] : 0;
        vals[j] = tsum;          // local exclusive prefix
        tsum += v;
    }
    int lane = tid & 63, wid = tid >> 6;
    int x = tsum;
    #pragma unroll
    for (int d = 1; d < 64; d <<= 1) { int y = __shfl_up(x, d); if (lane >= d) x += y; }
    if (lane == 63) wsum[wid] = x;
    __syncthreads();
    if (wid == 0 && lane < 16) {
        int wv = wsum[lane];
        #pragma unroll
        for (int d = 1; d < 16; d <<= 1) { int y = __shfl_up(wv, d); if (lane >= d) wv += y; }
        wsum[lane] = wv;         // inclusive wave totals
    }
    __syncthreads();
    int waveoff = (wid == 0) ? 0 : wsum[wid - 1];
    int ex = waveoff + (x - tsum);
    #pragma unroll
    for (int j = 0; j < 10; ++j) {
        int i = base + j;
        if (i < N_NODES) o[i] = ex + vals[j];
    }
    if (tid == 1023) o[N_NODES] = wsum[15];
}

__global__ __launch_bounds__(256) void fill_kernel(const int* __restrict__ adjs,
                                                   const int* __restrict__ offsets,
                                                   int* __restrict__ cursor,
                                                   int* __restrict__ esrc) {
    int idx = blockIdx.x * 256 + threadIdx.x;
    if (idx >= NSLOT * E_EDGES) return;
    int s = idx / E_EDGES;
    int e = idx - s * E_EDGES;
    const int* a = adjs + (size_t)(5 + s) * 2 * E_EDGES;
    int src = a[e];
    int dst = a[E_EDGES + e];
    int pos = atomicAdd(&cursor[s * N_NODES + dst], 1);
    esrc[(size_t)s * E_EDGES + offsets[s * (N_NODES + 1) + dst] + pos] = src;
}

// ---------------------------------------------------------------------------
// A @ X gather, fp16 rows, slot->XCD affinity.
// Grid = 8 * 2500 blocks; XCD = blockIdx & 7 (empirical round-robin), slot =
// XCD (XCD 7 idles). Confines each slot's 5.12MB source set to one XCD's L2.
// One wave per node; lane owns 4 halves (8B); edge loop unrolled x8.
// fp32 accumulate, fp16 out.
// ---------------------------------------------------------------------------
__global__ __launch_bounds__(256) void ax16_kernel(const f16* __restrict__ xin,
                                                   f16* __restrict__ xout,
                                                   const int* __restrict__ offsets,
                                                   const int* __restrict__ esrc) {
    int s = blockIdx.x & 7;
    if (s >= NSLOT) return;
    int n = ((blockIdx.x >> 3) << 2) + (threadIdx.x >> 6);
    int lane = threadIdx.x & 63;
    const int* off = offsets + s * (N_NODES + 1);
    int j0 = off[n], j1 = off[n + 1];
    const f16* base = xin + (size_t)s * N_NODES * F_DIM + lane * 4;
    const int* es = esrc + (size_t)s * E_EDGES;
    float ax = 0.f, ay = 0.f, az = 0.f, aw = 0.f;
    int j = j0;
    for (; j + 8 <= j1; j += 8) {
        int i0 = es[j], i1 = es[j+1], i2 = es[j+2], i3 = es[j+3];
        int i4 = es[j+4], i5 = es[j+5], i6 = es[j+6], i7 = es[j+7];
        f16x4 r0 = *(const f16x4*)(base + (size_t)i0 * F_DIM);
        f16x4 r1 = *(const f16x4*)(base + (size_t)i1 * F_DIM);
        f16x4 r2 = *(const f16x4*)(base + (size_t)i2 * F_DIM);
        f16x4 r3 = *(const f16x4*)(base + (size_t)i3 * F_DIM);
        f16x4 r4 = *(const f16x4*)(base + (size_t)i4 * F_DIM);
        f16x4 r5 = *(const f16x4*)(base + (size_t)i5 * F_DIM);
        f16x4 r6 = *(const f16x4*)(base + (size_t)i6 * F_DIM);
        f16x4 r7 = *(const f16x4*)(base + (size_t)i7 * F_DIM);
        ax += (((float)r0[0] + (float)r1[0]) + ((float)r2[0] + (float)r3[0]))
            + (((float)r4[0] + (float)r5[0]) + ((float)r6[0] + (float)r7[0]));
        ay += (((float)r0[1] + (float)r1[1]) + ((float)r2[1] + (float)r3[1]))
            + (((float)r4[1] + (float)r5[1]) + ((float)r6[1] + (float)r7[1]));
        az += (((float)r0[2] + (float)r1[2]) + ((float)r2[2] + (float)r3[2]))
            + (((float)r4[2] + (float)r5[2]) + ((float)r6[2] + (float)r7[2]));
        aw += (((float)r0[3] + (float)r1[3]) + ((float)r2[3] + (float)r3[3]))
            + (((float)r4[3] + (float)r5[3]) + ((float)r6[3] + (float)r7[3]));
    }
    for (; j < j1; ++j) {
        f16x4 r = *(const f16x4*)(base + (size_t)es[j] * F_DIM);
        ax += (float)r[0]; ay += (float)r[1]; az += (float)r[2]; aw += (float)r[3];
    }
    f16x4 o;
    o[0] = (f16)ax; o[1] = (f16)ay; o[2] = (f16)az; o[3] = (f16)aw;
    *(f16x4*)(xout + ((size_t)s * N_NODES + n) * F_DIM + lane * 4) = o;
}

// ---------------------------------------------------------------------------
// Weight pack: w[l][o][i][tap] (fp32) -> wTt fp16 [l][bo(4)][kk(24)][cg(2)][col(64)][k(32)]
// so each (l,bo,kk) B-block is a contiguous 8KB staged by linear global_load_lds.
// ---------------------------------------------------------------------------
__global__ __launch_bounds__(256) void wtrans16_kernel(const float* __restrict__ cw,
                                                       const float* __restrict__ gw,
                                                       f16* __restrict__ wTt) {
    int idx = blockIdx.x * 256 + threadIdx.x;
    if (idx >= 3 * 4 * 24 * 2 * 64 * 32) return;
    int k   = idx & 31;
    int col = (idx >> 5) & 63;
    int cg  = (idx >> 11) & 1;
    int r   = idx >> 12;            // (l*4 + bo)*24 + kk
    int lbo = r / 24;
    int kk  = r - lbo * 24;
    int l   = lbo >> 2, bo = lbo & 3;
    int K   = kk * 32 + k;
    int tap = K >> 8;
    int ci  = K & 255;
    int o   = bo * 64 + col;
    const float* src = cg ? gw : cw;
    wTt[idx] = (f16)src[(((size_t)l * 256 + o) * 256 + ci) * 3 + tap];
}

// ---------------------------------------------------------------------------
// Gated causal conv as fp16 MFMA GEMM (fp32 accumulate).
// Block: 256 thr = 4 waves; tile 128 rows x 64 cols, twin (conv+gate) B.
// TRIPLE-BUFFERED K-pipeline (T3/T4): stage K-step kk+2 while computing kk;
// counted s_waitcnt vmcnt(8) (= 4 loads/step x 2 steps in flight), raw
// s_barrier (NOT __syncthreads -- that would drain vmcnt to 0 per step).
// LDS: 3 bufs x (A[128][32] + B[2][64][32]) fp16 = 48KB -> 3 blocks/CU.
// ---------------------------------------------------------------------------
__global__ __launch_bounds__(256) void conv_gemm_f16_kernel(
    const f16* __restrict__ xin, f16* __restrict__ xout,
    const f16* __restrict__ wTt,           // this layer's [4][24][2][64][32]
    const float* __restrict__ biasc, const float* __restrict__ biasg,
    int M, int in_slot_base, int out_slot0)
{
    __shared__ __align__(16) f16 lds[3 * 8192];   // buf p at p*8192 halves

    const int tid = threadIdx.x;
    const int ln  = tid & 63;
    const int w   = __builtin_amdgcn_readfirstlane(tid >> 6);
    const int bm  = blockIdx.x, bo = blockIdx.y;
    const int wr  = w >> 1, wc = w & 1;

    // ---- staging address precompute (per lane) ----
    const size_t SLOTB = (size_t)N_NODES * F_DIM * 2;   // bytes per slot
    const char* xin_b = (const char*)xin + (size_t)in_slot_base * SLOTB;
    int r0  = 32 * w + (ln >> 2);
    int gr0 = bm * CG_BM + r0;      if (gr0 > M - 1) gr0 = M - 1;
    int gr1 = bm * CG_BM + r0 + 16; if (gr1 > M - 1) gr1 = M - 1;
    int sg0 = gr0 / N_NODES, nn0 = gr0 - sg0 * N_NODES;
    int sg1 = gr1 / N_NODES, nn1 = gr1 - sg1 * N_NODES;
    const char* aptr0 = xin_b + (size_t)sg0 * SLOTB + (size_t)nn0 * 512 + (ln & 3) * 16;
    const char* aptr1 = xin_b + (size_t)sg1 * SLOTB + (size_t)nn1 * 512 + (ln & 3) * 16;
    const char* bptr  = (const char*)wTt + (size_t)bo * (24 * 8192)
                        + (size_t)(2 * w) * 1024 + (size_t)ln * 16;

    // fragment read offsets, relative to buffer base (half-index)
    const int aoff = (wr * 64 + (ln & 15)) * 32 + (ln >> 4) * 8;
    const int boff = 4096 + (wc * 32 + (ln & 15)) * 32 + (ln >> 4) * 8;

    f32x4 acc_c[4][2] = {};
    f32x4 acc_g[4][2] = {};

    // stage K-step kk into buffer p (4 x global_load_lds, 16KB per block)
    auto STAGE = [&](int kk, int p) {
        const size_t aoffb = (size_t)(kk >> 3) * SLOTB + (size_t)(kk & 7) * 64;
        const char* gb = bptr + (size_t)kk * 8192;
        f16* base = lds + p * 8192;
        glds16(aptr0 + aoffb, base + (2 * w    ) * 512);
        glds16(aptr1 + aoffb, base + (2 * w + 1) * 512);
        glds16(gb,        base + 4096 + (2 * w    ) * 512);
        glds16(gb + 1024, base + 4096 + (2 * w + 1) * 512);
    };

    // prologue: two K-steps in flight
    STAGE(0, 0);
    STAGE(1, 1);

    #pragma unroll
    for (int kk = 0; kk < 24; ++kk) {
        const int p = kk % 3;
        if (kk < 22) {
            STAGE(kk + 2, (kk + 2) % 3);
            asm volatile("s_waitcnt vmcnt(8)" ::: "memory");   // step kk's 4 loads done
        } else if (kk == 22) {
            asm volatile("s_waitcnt vmcnt(4)" ::: "memory");
        } else {
            asm volatile("s_waitcnt vmcnt(0)" ::: "memory");
        }
        __builtin_amdgcn_s_barrier();   // buf p visible to all waves

        const f16* L = lds + p * 8192;
        f16x8 af0 = *(const f16x8*)&L[aoff];
        f16x8 af1 = *(const f16x8*)&L[aoff + 512];
        f16x8 af2 = *(const f16x8*)&L[aoff + 1024];
        f16x8 af3 = *(const f16x8*)&L[aoff + 1536];
        f16x8 bc0 = *(const f16x8*)&L[boff];
        f16x8 bc1 = *(const f16x8*)&L[boff + 512];
        f16x8 bg0 = *(const f16x8*)&L[boff + 2048];
        f16x8 bg1 = *(const f16x8*)&L[boff + 2560];

        acc_c[0][0] = __builtin_amdgcn_mfma_f32_16x16x32_f16(af0, bc0, acc_c[0][0], 0, 0, 0);
        acc_g[0][0] = __builtin_amdgcn_mfma_f32_16x16x32_f16(af0, bg0, acc_g[0][0], 0, 0, 0);
        acc_c[0][1] = __builtin_amdgcn_mfma_f32_16x16x32_f16(af0, bc1, acc_c[0][1], 0, 0, 0);
        acc_g[0][1] = __builtin_amdgcn_mfma_f32_16x16x32_f16(af0, bg1, acc_g[0][1], 0, 0, 0);
        acc_c[1][0] = __builtin_amdgcn_mfma_f32_16x16x32_f16(af1, bc0, acc_c[1][0], 0, 0, 0);
        acc_g[1][0] = __builtin_amdgcn_mfma_f32_16x16x32_f16(af1, bg0, acc_g[1][0], 0, 0, 0);
        acc_c[1][1] = __builtin_amdgcn_mfma_f32_16x16x32_f16(af1, bc1, acc_c[1][1], 0, 0, 0);
        acc_g[1][1] = __builtin_amdgcn_mfma_f32_16x16x32_f16(af1, bg1, acc_g[1][1], 0, 0, 0);
        acc_c[2][0] = __builtin_amdgcn_mfma_f32_16x16x32_f16(af2, bc0, acc_c[2][0], 0, 0, 0);
        acc_g[2][0] = __builtin_amdgcn_mfma_f32_16x16x32_f16(af2, bg0, acc_g[2][0], 0, 0, 0);
        acc_c[2][1] = __builtin_amdgcn_mfma_f32_16x16x32_f16(af2, bc1, acc_c[2][1], 0, 0, 0);
        acc_g[2][1] = __builtin_amdgcn_mfma_f32_16x16x32_f16(af2, bg1, acc_g[2][1], 0, 0, 0);
        acc_c[3][0] = __builtin_amdgcn_mfma_f32_16x16x32_f16(af3, bc0, acc_c[3][0], 0, 0, 0);
        acc_g[3][0] = __builtin_amdgcn_mfma_f32_16x16x32_f16(af3, bg0, acc_g[3][0], 0, 0, 0);
        acc_c[3][1] = __builtin_amdgcn_mfma_f32_16x16x32_f16(af3, bc1, acc_c[3][1], 0, 0, 0);
        acc_g[3][1] = __builtin_amdgcn_mfma_f32_16x16x32_f16(af3, bg1, acc_g[3][1], 0, 0, 0);

        __builtin_amdgcn_s_barrier();   // all reads of buf p done before restage
    }
    __builtin_amdgcn_sched_barrier(0);  // keep epilogue VMEM out of counted region

    // epilogue: D layout col = lane&15, row = (lane>>4)*4 + reg  [m89-verified]
    #pragma unroll
    for (int rb = 0; rb < 4; ++rb) {
        int grow0 = bm * CG_BM + wr * 64 + rb * 16 + ((ln >> 4) << 2);
        #pragma unroll
        for (int cf = 0; cf < 2; ++cf) {
            int gcol = bo * 64 + wc * 32 + cf * 16 + (ln & 15);
            float bc = biasc[gcol], bg = biasg[gcol];
            #pragma unroll
            for (int r = 0; r < 4; ++r) {
                int grow = grow0 + r;
                if (grow < M) {
                    int sg = grow / N_NODES;
                    int nn = grow - sg * N_NODES;
                    float cv = acc_c[rb][cf][r] + bc;
                    float gv = acc_g[rb][cf][r] + bg;
                    float y  = cv / (1.0f + expf(-gv));
                    xout[((size_t)(out_slot0 + sg) * N_NODES + nn) * F_DIM + gcol] = (f16)y;
                }
            }
        }
    }
}

// ---------------------------------------------------------------------------
// Head: out[n] = log_softmax(emb_row(fp16) @ lin_w.T + lin_b). One wave/node.
// ---------------------------------------------------------------------------
__global__ __launch_bounds__(64) void head_kernel(const f16* __restrict__ emb,    // [N][F] slot 6
                                                  const float* __restrict__ lin_w, // [64][256]
                                                  const float* __restrict__ lin_b,
                                                  float* __restrict__ out) {
    int n = blockIdx.x;
    int tid = threadIdx.x;   // 0..63 = output channel
    __shared__ float row[F_DIM];
    f16x4 hv = *(const f16x4*)(emb + (size_t)n * F_DIM + tid * 4);
    row[tid * 4 + 0] = (float)hv[0];
    row[tid * 4 + 1] = (float)hv[1];
    row[tid * 4 + 2] = (float)hv[2];
    row[tid * 4 + 3] = (float)hv[3];
    __syncthreads();
    float acc = lin_b[tid];
    const float* w = lin_w + (size_t)tid * F_DIM;
    #pragma unroll 8
    for (int c = 0; c < F_DIM; c += 4) {
        float4 wv = *(const float4*)(w + c);
        acc += row[c] * wv.x + row[c + 1] * wv.y + row[c + 2] * wv.z + row[c + 3] * wv.w;
    }
    float mx = acc;
    #pragma unroll
    for (int s = 32; s > 0; s >>= 1) mx = fmaxf(mx, __shfl_xor(mx, s));
    float ex = expf(acc - mx);
    float sum = ex;
    #pragma unroll
    for (int s = 32; s > 0; s >>= 1) sum += __shfl_xor(sum, s);
    out[(size_t)n * OUT_DIM + tid] = acc - mx - logf(sum);
}

// ---------------------------------------------------------------------------
extern "C" void kernel_launch(void* const* d_in, const int* in_sizes, int n_in,
                              void* d_out, int out_size, void* d_ws, size_t ws_size,
                              hipStream_t stream) {
    (void)in_sizes; (void)n_in; (void)out_size; (void)ws_size;
    const float* feats  = (const float*)d_in[0];
    const int*   adjs   = (const int*)d_in[1];
    const float* conv_w = (const float*)d_in[2];
    const float* conv_b = (const float*)d_in[3];
    const float* gate_w = (const float*)d_in[4];
    const float* gate_b = (const float*)d_in[5];
    const float* lin_w  = (const float*)d_in[6];
    const float* lin_b  = (const float*)d_in[7];
    float* out = (float*)d_out;

    char* ws = (char*)d_ws;
    const size_t SX16 = (size_t)NSLOT * N_NODES * F_DIM * 2;  // 35,840,000 B
    const size_t OXF  = 0;                    // x16f (feats fp16)
    const size_t OXP  = OXF + SX16;           // x16p (hop1 out)
    const size_t OXA  = OXP + SX16;           // x16a (hop2 out / conv ping)
    const size_t OXB  = OXA + SX16;           // x16b (conv pong)
    const size_t OWT  = OXB + SX16;           // wTt:      2,359,296 B
    const size_t OCN  = OWT + 2359296;        // counts:     280,000 B
    const size_t OOF  = OCN + 280000;         // offsets:    280,064 B (padded)
    const size_t OES  = OOF + 280064;         // esrc:     4,480,000 B

    f16*   x16f    = (f16*)  (ws + OXF);
    f16*   x16p    = (f16*)  (ws + OXP);
    f16*   x16a    = (f16*)  (ws + OXA);
    f16*   x16b    = (f16*)  (ws + OXB);
    f16*   wTt     = (f16*)  (ws + OWT);
    int*   counts  = (int*)  (ws + OCN);
    int*   offsets = (int*)  (ws + OOF);
    int*   esrc    = (int*)  (ws + OES);

    const int ncnt = NSLOT * N_NODES;
    const int nedge_thr = NSLOT * E_EDGES;
    const int LWT = 4 * 24 * 2 * 64 * 32;     // halves per layer in wTt
    const int nconv8 = NSLOT * N_NODES * F_DIM / 8;  // convert threads

    // --- CSR build for slots 0..6 (t = 5..11) ---
    zero_i32_kernel<<<(ncnt + 255) / 256, 256, 0, stream>>>(counts, ncnt);
    count_kernel<<<(nedge_thr + 255) / 256, 256, 0, stream>>>(adjs, counts);
    scan_kernel<<<NSLOT, 1024, 0, stream>>>(counts, offsets);
    zero_i32_kernel<<<(ncnt + 255) / 256, 256, 0, stream>>>(counts, ncnt);  // reuse as cursor
    fill_kernel<<<(nedge_thr + 255) / 256, 256, 0, stream>>>(adjs, offsets, counts, esrc);

    wtrans16_kernel<<<(3 * LWT + 255) / 256, 256, 0, stream>>>(conv_w, gate_w, wTt);
    feats2f16_kernel<<<(nconv8 + 255) / 256, 256, 0, stream>>>(feats, x16f);

    // --- graph conv, fp16 gathers with slot->XCD affinity (8*2500 blocks) ---
    ax16_kernel<<<8 * (N_NODES / 4), 256, 0, stream>>>(x16f, x16p, offsets, esrc);
    ax16_kernel<<<8 * (N_NODES / 4), 256, 0, stream>>>(x16p, x16a, offsets, esrc);

    // --- gated TCN layers (fp16 MFMA GEMMs) ---
    const int M0 = 5 * N_NODES;   // out slots 2..6, reads 0..6
    conv_gemm_f16_kernel<<<dim3((M0 + CG_BM - 1) / CG_BM, 4), 256, 0, stream>>>(
        x16a, x16b, wTt, conv_b, gate_b, M0, 0, 2);
    const int M1 = 3 * N_NODES;   // out slots 4..6, reads 2..6
    conv_gemm_f16_kernel<<<dim3((M1 + CG_BM - 1) / CG_BM, 4), 256, 0, stream>>>(
        x16b, x16a, wTt + LWT, conv_b + 256, gate_b + 256, M1, 2, 4);
    const int M2 = 1 * N_NODES;   // out slot 6, reads 4..6
    conv_gemm_f16_kernel<<<dim3((M2 + CG_BM - 1) / CG_BM, 4), 256, 0, stream>>>(
        x16a, x16b, wTt + 2 * LWT, conv_b + 512, gate_b + 512, M2, 4, 6);

    // --- head: linear + log_softmax on slot 6 ---
    head_kernel<<<N_NODES, 64, 0, stream>>>(x16b + (size_t)6 * N_NODES * F_DIM, lin_w, lin_b, out);
}

// Round 9
// 566.703 us; speedup vs baseline: 3.1740x; 1.1083x over previous
//
#include <hip/hip_runtime.h>
#include <cstdint>
#include <cstddef>

#define T_DIM   12
#define N_NODES 10000
#define F_DIM   256
#define E_EDGES 160000
#define NSLOT   7     // timesteps 5..11 are the only ones that matter
#define OUT_DIM 64
#define CG_BM   128

typedef _Float16 f16;
typedef _Float16 f16x8 __attribute__((ext_vector_type(8)));
typedef _Float16 f16x4 __attribute__((ext_vector_type(4)));
typedef float    f32x4 __attribute__((ext_vector_type(4)));

typedef __attribute__((address_space(1))) const void* as1_cvp;
typedef __attribute__((address_space(3))) void*       as3_vp;

__device__ __forceinline__ void glds16(const void* g, void* l) {
    __builtin_amdgcn_global_load_lds((as1_cvp)g, (as3_vp)l, 16, 0, 0);
}

// ---------------------------------------------------------------------------
// Zero helper (keep capture stream pure-kernel)
// ---------------------------------------------------------------------------
__global__ __launch_bounds__(256) void zero_i32_kernel(int* __restrict__ p, int n) {
    int i = blockIdx.x * 256 + threadIdx.x;
    if (i < n) p[i] = 0;
}

// ---------------------------------------------------------------------------
// feats (fp32, slots 5..11) -> fp16, streaming. 8 floats per thread.
// ---------------------------------------------------------------------------
__global__ __launch_bounds__(256) void feats2f16_kernel(const float* __restrict__ feats,
                                                        f16* __restrict__ xout) {
    int idx = blockIdx.x * 256 + threadIdx.x;   // 8 floats each
    const int total = NSLOT * N_NODES * F_DIM;  // 17,920,000
    int i0 = idx * 8;
    if (i0 >= total) return;
    const float* src = feats + (size_t)5 * N_NODES * F_DIM + i0;
    float4 a = *(const float4*)src;
    float4 b = *(const float4*)(src + 4);
    f16x8 o;
    o[0] = (f16)a.x; o[1] = (f16)a.y; o[2] = (f16)a.z; o[3] = (f16)a.w;
    o[4] = (f16)b.x; o[5] = (f16)b.y; o[6] = (f16)b.z; o[7] = (f16)b.w;
    *(f16x8*)(xout + i0) = o;
}

// ---------------------------------------------------------------------------
// CSR build
// ---------------------------------------------------------------------------
__global__ __launch_bounds__(256) void count_kernel(const int* __restrict__ adjs,
                                                    int* __restrict__ counts) {
    int idx = blockIdx.x * 256 + threadIdx.x;
    if (idx >= NSLOT * E_EDGES) return;
    int s = idx / E_EDGES;
    int e = idx - s * E_EDGES;
    int dst = adjs[(size_t)(5 + s) * 2 * E_EDGES + E_EDGES + e];
    atomicAdd(&counts[s * N_NODES + dst], 1);
}

// 2-barrier scan: each thread owns 10 nodes, shfl wave-scan + cross-wave scan.
__global__ __launch_bounds__(1024) void scan_kernel(const int* __restrict__ counts,
                                                    int* __restrict__ offsets) {
    int s = blockIdx.x, tid = threadIdx.x;
    const int* c = counts + s * N_NODES;
    int* o = offsets + s * (N_NODES + 1);
    __shared__ int wsum[16];
    int vals[10];
    int tsum = 0;
    int base = tid * 10;
    #pragma unroll
    for (int j = 0; j < 10; ++j) {
        int i = base + j;
        int v = (i < N_NODES) ? c[i] : 0;
        vals[j] = tsum;          // local exclusive prefix
        tsum += v;
    }
    int lane = tid & 63, wid = tid >> 6;
    int x = tsum;
    #pragma unroll
    for (int d = 1; d < 64; d <<= 1) { int y = __shfl_up(x, d); if (lane >= d) x += y; }
    if (lane == 63) wsum[wid] = x;
    __syncthreads();
    if (wid == 0 && lane < 16) {
        int wv = wsum[lane];
        #pragma unroll
        for (int d = 1; d < 16; d <<= 1) { int y = __shfl_up(wv, d); if (lane >= d) wv += y; }
        wsum[lane] = wv;         // inclusive wave totals
    }
    __syncthreads();
    int waveoff = (wid == 0) ? 0 : wsum[wid - 1];
    int ex = waveoff + (x - tsum);
    #pragma unroll
    for (int j = 0; j < 10; ++j) {
        int i = base + j;
        if (i < N_NODES) o[i] = ex + vals[j];
    }
    if (tid == 1023) o[N_NODES] = wsum[15];
}

__global__ __launch_bounds__(256) void fill_kernel(const int* __restrict__ adjs,
                                                   const int* __restrict__ offsets,
                                                   int* __restrict__ cursor,
                                                   int* __restrict__ esrc) {
    int idx = blockIdx.x * 256 + threadIdx.x;
    if (idx >= NSLOT * E_EDGES) return;
    int s = idx / E_EDGES;
    int e = idx - s * E_EDGES;
    const int* a = adjs + (size_t)(5 + s) * 2 * E_EDGES;
    int src = a[e];
    int dst = a[E_EDGES + e];
    int pos = atomicAdd(&cursor[s * N_NODES + dst], 1);
    esrc[(size_t)s * E_EDGES + offsets[s * (N_NODES + 1) + dst] + pos] = src;
}

// ---------------------------------------------------------------------------
// A @ X gather, fp16 rows, slot->XCD affinity.
// Grid = 8 * 2500 blocks; XCD = blockIdx & 7 (empirical round-robin), slot =
// XCD (XCD 7 idles). Confines each slot's 5.12MB source set to one XCD's L2.
// One wave per node; lane owns 4 halves (8B); edge loop unrolled x8.
// fp32 accumulate, fp16 out.
// ---------------------------------------------------------------------------
__global__ __launch_bounds__(256) void ax16_kernel(const f16* __restrict__ xin,
                                                   f16* __restrict__ xout,
                                                   const int* __restrict__ offsets,
                                                   const int* __restrict__ esrc) {
    int s = blockIdx.x & 7;
    if (s >= NSLOT) return;
    int n = ((blockIdx.x >> 3) << 2) + (threadIdx.x >> 6);
    int lane = threadIdx.x & 63;
    const int* off = offsets + s * (N_NODES + 1);
    int j0 = off[n], j1 = off[n + 1];
    const f16* base = xin + (size_t)s * N_NODES * F_DIM + lane * 4;
    const int* es = esrc + (size_t)s * E_EDGES;
    float ax = 0.f, ay = 0.f, az = 0.f, aw = 0.f;
    int j = j0;
    for (; j + 8 <= j1; j += 8) {
        int i0 = es[j], i1 = es[j+1], i2 = es[j+2], i3 = es[j+3];
        int i4 = es[j+4], i5 = es[j+5], i6 = es[j+6], i7 = es[j+7];
        f16x4 r0 = *(const f16x4*)(base + (size_t)i0 * F_DIM);
        f16x4 r1 = *(const f16x4*)(base + (size_t)i1 * F_DIM);
        f16x4 r2 = *(const f16x4*)(base + (size_t)i2 * F_DIM);
        f16x4 r3 = *(const f16x4*)(base + (size_t)i3 * F_DIM);
        f16x4 r4 = *(const f16x4*)(base + (size_t)i4 * F_DIM);
        f16x4 r5 = *(const f16x4*)(base + (size_t)i5 * F_DIM);
        f16x4 r6 = *(const f16x4*)(base + (size_t)i6 * F_DIM);
        f16x4 r7 = *(const f16x4*)(base + (size_t)i7 * F_DIM);
        ax += (((float)r0[0] + (float)r1[0]) + ((float)r2[0] + (float)r3[0]))
            + (((float)r4[0] + (float)r5[0]) + ((float)r6[0] + (float)r7[0]));
        ay += (((float)r0[1] + (float)r1[1]) + ((float)r2[1] + (float)r3[1]))
            + (((float)r4[1] + (float)r5[1]) + ((float)r6[1] + (float)r7[1]));
        az += (((float)r0[2] + (float)r1[2]) + ((float)r2[2] + (float)r3[2]))
            + (((float)r4[2] + (float)r5[2]) + ((float)r6[2] + (float)r7[2]));
        aw += (((float)r0[3] + (float)r1[3]) + ((float)r2[3] + (float)r3[3]))
            + (((float)r4[3] + (float)r5[3]) + ((float)r6[3] + (float)r7[3]));
    }
    for (; j < j1; ++j) {
        f16x4 r = *(const f16x4*)(base + (size_t)es[j] * F_DIM);
        ax += (float)r[0]; ay += (float)r[1]; az += (float)r[2]; aw += (float)r[3];
    }
    f16x4 o;
    o[0] = (f16)ax; o[1] = (f16)ay; o[2] = (f16)az; o[3] = (f16)aw;
    *(f16x4*)(xout + ((size_t)s * N_NODES + n) * F_DIM + lane * 4) = o;
}

// ---------------------------------------------------------------------------
// Weight pack: w[l][o][i][tap] (fp32) -> wTt fp16 [l][bo(4)][kk(24)][cg(2)][col(64)][k(32)]
// so each (l,bo,kk) B-block is a contiguous 8KB staged by linear global_load_lds.
// ---------------------------------------------------------------------------
__global__ __launch_bounds__(256) void wtrans16_kernel(const float* __restrict__ cw,
                                                       const float* __restrict__ gw,
                                                       f16* __restrict__ wTt) {
    int idx = blockIdx.x * 256 + threadIdx.x;
    if (idx >= 3 * 4 * 24 * 2 * 64 * 32) return;
    int k   = idx & 31;
    int col = (idx >> 5) & 63;
    int cg  = (idx >> 11) & 1;
    int r   = idx >> 12;            // (l*4 + bo)*24 + kk
    int lbo = r / 24;
    int kk  = r - lbo * 24;
    int l   = lbo >> 2, bo = lbo & 3;
    int K   = kk * 32 + k;
    int tap = K >> 8;
    int ci  = K & 255;
    int o   = bo * 64 + col;
    const float* src = cg ? gw : cw;
    wTt[idx] = (f16)src[(((size_t)l * 256 + o) * 256 + ci) * 3 + tap];
}

// ---------------------------------------------------------------------------
// Head weight pack: lin_w[o][i] fp32 -> wH fp16 [ks(8)][cf(4)][col(16)][k(32)]
// (B-fragment order for mfma_f32_16x16x32_f16; o = cf*16+col, i = ks*32+k)
// ---------------------------------------------------------------------------
__global__ __launch_bounds__(256) void whead_kernel(const float* __restrict__ lw,
                                                    f16* __restrict__ wH) {
    int idx = blockIdx.x * 256 + threadIdx.x;
    if (idx >= 8 * 4 * 16 * 32) return;
    int k   = idx & 31;
    int col = (idx >> 5) & 15;
    int cf  = (idx >> 9) & 3;
    int ks  = idx >> 11;
    int o   = cf * 16 + col;
    int i   = ks * 32 + k;
    wH[idx] = (f16)lw[o * 256 + i];
}

// ---------------------------------------------------------------------------
// Gated causal conv as fp16 MFMA GEMM (fp32 accumulate).
// Block: 256 thr = 4 waves; tile 128 rows x 64 cols, twin (conv+gate) B.
// TRIPLE-BUFFERED K-pipeline (T3/T4): stage K-step kk+2 while computing kk;
// counted s_waitcnt vmcnt(8) (= 4 loads/step x 2 steps in flight), raw
// s_barrier (NOT __syncthreads -- that would drain vmcnt to 0 per step).
// LDS: 3 bufs x (A[128][32] + B[2][64][32]) fp16 = 48KB -> 3 blocks/CU.
// ---------------------------------------------------------------------------
__global__ __launch_bounds__(256) void conv_gemm_f16_kernel(
    const f16* __restrict__ xin, f16* __restrict__ xout,
    const f16* __restrict__ wTt,           // this layer's [4][24][2][64][32]
    const float* __restrict__ biasc, const float* __restrict__ biasg,
    int M, int in_slot_base, int out_slot0)
{
    __shared__ __align__(16) f16 lds[3 * 8192];   // buf p at p*8192 halves

    const int tid = threadIdx.x;
    const int ln  = tid & 63;
    const int w   = __builtin_amdgcn_readfirstlane(tid >> 6);
    const int bm  = blockIdx.x, bo = blockIdx.y;
    const int wr  = w >> 1, wc = w & 1;

    // ---- staging address precompute (per lane) ----
    const size_t SLOTB = (size_t)N_NODES * F_DIM * 2;   // bytes per slot
    const char* xin_b = (const char*)xin + (size_t)in_slot_base * SLOTB;
    int r0  = 32 * w + (ln >> 2);
    int gr0 = bm * CG_BM + r0;      if (gr0 > M - 1) gr0 = M - 1;
    int gr1 = bm * CG_BM + r0 + 16; if (gr1 > M - 1) gr1 = M - 1;
    int sg0 = gr0 / N_NODES, nn0 = gr0 - sg0 * N_NODES;
    int sg1 = gr1 / N_NODES, nn1 = gr1 - sg1 * N_NODES;
    const char* aptr0 = xin_b + (size_t)sg0 * SLOTB + (size_t)nn0 * 512 + (ln & 3) * 16;
    const char* aptr1 = xin_b + (size_t)sg1 * SLOTB + (size_t)nn1 * 512 + (ln & 3) * 16;
    const char* bptr  = (const char*)wTt + (size_t)bo * (24 * 8192)
                        + (size_t)(2 * w) * 1024 + (size_t)ln * 16;

    // fragment read offsets, relative to buffer base (half-index)
    const int aoff = (wr * 64 + (ln & 15)) * 32 + (ln >> 4) * 8;
    const int boff = 4096 + (wc * 32 + (ln & 15)) * 32 + (ln >> 4) * 8;

    f32x4 acc_c[4][2] = {};
    f32x4 acc_g[4][2] = {};

    // stage K-step kk into buffer p (4 x global_load_lds, 16KB per block)
    auto STAGE = [&](int kk, int p) {
        const size_t aoffb = (size_t)(kk >> 3) * SLOTB + (size_t)(kk & 7) * 64;
        const char* gb = bptr + (size_t)kk * 8192;
        f16* base = lds + p * 8192;
        glds16(aptr0 + aoffb, base + (2 * w    ) * 512);
        glds16(aptr1 + aoffb, base + (2 * w + 1) * 512);
        glds16(gb,        base + 4096 + (2 * w    ) * 512);
        glds16(gb + 1024, base + 4096 + (2 * w + 1) * 512);
    };

    // prologue: two K-steps in flight
    STAGE(0, 0);
    STAGE(1, 1);

    #pragma unroll
    for (int kk = 0; kk < 24; ++kk) {
        const int p = kk % 3;
        if (kk < 22) {
            STAGE(kk + 2, (kk + 2) % 3);
            asm volatile("s_waitcnt vmcnt(8)" ::: "memory");   // step kk's 4 loads done
        } else if (kk == 22) {
            asm volatile("s_waitcnt vmcnt(4)" ::: "memory");
        } else {
            asm volatile("s_waitcnt vmcnt(0)" ::: "memory");
        }
        __builtin_amdgcn_s_barrier();   // buf p visible to all waves

        const f16* L = lds + p * 8192;
        f16x8 af0 = *(const f16x8*)&L[aoff];
        f16x8 af1 = *(const f16x8*)&L[aoff + 512];
        f16x8 af2 = *(const f16x8*)&L[aoff + 1024];
        f16x8 af3 = *(const f16x8*)&L[aoff + 1536];
        f16x8 bc0 = *(const f16x8*)&L[boff];
        f16x8 bc1 = *(const f16x8*)&L[boff + 512];
        f16x8 bg0 = *(const f16x8*)&L[boff + 2048];
        f16x8 bg1 = *(const f16x8*)&L[boff + 2560];

        acc_c[0][0] = __builtin_amdgcn_mfma_f32_16x16x32_f16(af0, bc0, acc_c[0][0], 0, 0, 0);
        acc_g[0][0] = __builtin_amdgcn_mfma_f32_16x16x32_f16(af0, bg0, acc_g[0][0], 0, 0, 0);
        acc_c[0][1] = __builtin_amdgcn_mfma_f32_16x16x32_f16(af0, bc1, acc_c[0][1], 0, 0, 0);
        acc_g[0][1] = __builtin_amdgcn_mfma_f32_16x16x32_f16(af0, bg1, acc_g[0][1], 0, 0, 0);
        acc_c[1][0] = __builtin_amdgcn_mfma_f32_16x16x32_f16(af1, bc0, acc_c[1][0], 0, 0, 0);
        acc_g[1][0] = __builtin_amdgcn_mfma_f32_16x16x32_f16(af1, bg0, acc_g[1][0], 0, 0, 0);
        acc_c[1][1] = __builtin_amdgcn_mfma_f32_16x16x32_f16(af1, bc1, acc_c[1][1], 0, 0, 0);
        acc_g[1][1] = __builtin_amdgcn_mfma_f32_16x16x32_f16(af1, bg1, acc_g[1][1], 0, 0, 0);
        acc_c[2][0] = __builtin_amdgcn_mfma_f32_16x16x32_f16(af2, bc0, acc_c[2][0], 0, 0, 0);
        acc_g[2][0] = __builtin_amdgcn_mfma_f32_16x16x32_f16(af2, bg0, acc_g[2][0], 0, 0, 0);
        acc_c[2][1] = __builtin_amdgcn_mfma_f32_16x16x32_f16(af2, bc1, acc_c[2][1], 0, 0, 0);
        acc_g[2][1] = __builtin_amdgcn_mfma_f32_16x16x32_f16(af2, bg1, acc_g[2][1], 0, 0, 0);
        acc_c[3][0] = __builtin_amdgcn_mfma_f32_16x16x32_f16(af3, bc0, acc_c[3][0], 0, 0, 0);
        acc_g[3][0] = __builtin_amdgcn_mfma_f32_16x16x32_f16(af3, bg0, acc_g[3][0], 0, 0, 0);
        acc_c[3][1] = __builtin_amdgcn_mfma_f32_16x16x32_f16(af3, bc1, acc_c[3][1], 0, 0, 0);
        acc_g[3][1] = __builtin_amdgcn_mfma_f32_16x16x32_f16(af3, bg1, acc_g[3][1], 0, 0, 0);

        __builtin_amdgcn_s_barrier();   // all reads of buf p done before restage
    }
    __builtin_amdgcn_sched_barrier(0);  // keep epilogue VMEM out of counted region

    // epilogue: D layout col = lane&15, row = (lane>>4)*4 + reg  [m89-verified]
    #pragma unroll
    for (int rb = 0; rb < 4; ++rb) {
        int grow0 = bm * CG_BM + wr * 64 + rb * 16 + ((ln >> 4) << 2);
        #pragma unroll
        for (int cf = 0; cf < 2; ++cf) {
            int gcol = bo * 64 + wc * 32 + cf * 16 + (ln & 15);
            float bc = biasc[gcol], bg = biasg[gcol];
            #pragma unroll
            for (int r = 0; r < 4; ++r) {
                int grow = grow0 + r;
                if (grow < M) {
                    int sg = grow / N_NODES;
                    int nn = grow - sg * N_NODES;
                    float cv = acc_c[rb][cf][r] + bc;
                    float gv = acc_g[rb][cf][r] + bg;
                    float y  = cv / (1.0f + expf(-gv));
                    xout[((size_t)(out_slot0 + sg) * N_NODES + nn) * F_DIM + gcol] = (f16)y;
                }
            }
        }
    }
}

// ---------------------------------------------------------------------------
// Head as MFMA GEMM + in-register log_softmax.
// Block: 256 thr = 4 waves; wave handles 16 nodes x 64 outch via 4 col-frags
// x 8 K-steps of mfma_f32_16x16x32_f16. A frags straight from global (fp16
// emb rows); B frags from wH (fragment-packed, coalesced, L2-resident).
// Softmax: in-lane max/sum over 4 cfs, then shfl_xor over the 16-lane col
// group (masks 1,2,4,8 keep the (ln>>4) node group).
// ---------------------------------------------------------------------------
__global__ __launch_bounds__(256) void head_mfma_kernel(const f16* __restrict__ emb,
                                                        const f16* __restrict__ wH,
                                                        const float* __restrict__ lin_b,
                                                        float* __restrict__ out) {
    const int ln = threadIdx.x & 63;
    const int w  = threadIdx.x >> 6;
    const int nb = blockIdx.x * 64 + w * 16;
    if (nb >= N_NODES) return;

    const f16* arow = emb + (size_t)(nb + (ln & 15)) * F_DIM + (ln >> 4) * 8;
    const f16* wb   = wH + (ln & 15) * 32 + (ln >> 4) * 8;

    f32x4 acc[4] = {};
    #pragma unroll
    for (int ks = 0; ks < 8; ++ks) {
        f16x8 a = *(const f16x8*)(arow + ks * 32);
        const f16* wk = wb + ks * 2048;
        #pragma unroll
        for (int cf = 0; cf < 4; ++cf) {
            f16x8 b = *(const f16x8*)(wk + cf * 512);
            acc[cf] = __builtin_amdgcn_mfma_f32_16x16x32_f16(a, b, acc[cf], 0, 0, 0);
        }
    }

    // bias
    float v[4][4];
    #pragma unroll
    for (int cf = 0; cf < 4; ++cf) {
        float bb = lin_b[cf * 16 + (ln & 15)];
        #pragma unroll
        for (int r = 0; r < 4; ++r) v[cf][r] = acc[cf][r] + bb;
    }

    // per node-row (r): log_softmax over 64 outch = 4 cf x 16 lanes
    #pragma unroll
    for (int r = 0; r < 4; ++r) {
        float m = fmaxf(fmaxf(v[0][r], v[1][r]), fmaxf(v[2][r], v[3][r]));
        #pragma unroll
        for (int d = 1; d < 16; d <<= 1) m = fmaxf(m, __shfl_xor(m, d));
        float s = expf(v[0][r] - m) + expf(v[1][r] - m)
                + expf(v[2][r] - m) + expf(v[3][r] - m);
        #pragma unroll
        for (int d = 1; d < 16; d <<= 1) s += __shfl_xor(s, d);
        float ls = m + logf(s);
        int node = nb + (ln >> 4) * 4 + r;
        float* o = out + (size_t)node * OUT_DIM + (ln & 15);
        #pragma unroll
        for (int cf = 0; cf < 4; ++cf) o[cf * 16] = v[cf][r] - ls;
    }
}

// ---------------------------------------------------------------------------
extern "C" void kernel_launch(void* const* d_in, const int* in_sizes, int n_in,
                              void* d_out, int out_size, void* d_ws, size_t ws_size,
                              hipStream_t stream) {
    (void)in_sizes; (void)n_in; (void)out_size; (void)ws_size;
    const float* feats  = (const float*)d_in[0];
    const int*   adjs   = (const int*)d_in[1];
    const float* conv_w = (const float*)d_in[2];
    const float* conv_b = (const float*)d_in[3];
    const float* gate_w = (const float*)d_in[4];
    const float* gate_b = (const float*)d_in[5];
    const float* lin_w  = (const float*)d_in[6];
    const float* lin_b  = (const float*)d_in[7];
    float* out = (float*)d_out;

    char* ws = (char*)d_ws;
    const size_t SX16 = (size_t)NSLOT * N_NODES * F_DIM * 2;  // 35,840,000 B
    const size_t OXF  = 0;                    // x16f (feats fp16)
    const size_t OXP  = OXF + SX16;           // x16p (hop1 out)
    const size_t OXA  = OXP + SX16;           // x16a (hop2 out / conv ping)
    const size_t OXB  = OXA + SX16;           // x16b (conv pong)
    const size_t OWT  = OXB + SX16;           // wTt:      2,359,296 B
    const size_t OCN  = OWT + 2359296;        // counts:     280,000 B
    const size_t OOF  = OCN + 280000;         // offsets:    280,064 B (padded)
    const size_t OES  = OOF + 280064;         // esrc:     4,480,000 B
    const size_t OWH  = OES + 4480000;        // wH (head): 32,768 B

    f16*   x16f    = (f16*)  (ws + OXF);
    f16*   x16p    = (f16*)  (ws + OXP);
    f16*   x16a    = (f16*)  (ws + OXA);
    f16*   x16b    = (f16*)  (ws + OXB);
    f16*   wTt     = (f16*)  (ws + OWT);
    int*   counts  = (int*)  (ws + OCN);
    int*   offsets = (int*)  (ws + OOF);
    int*   esrc    = (int*)  (ws + OES);
    f16*   wH      = (f16*)  (ws + OWH);

    const int ncnt = NSLOT * N_NODES;
    const int nedge_thr = NSLOT * E_EDGES;
    const int LWT = 4 * 24 * 2 * 64 * 32;     // halves per layer in wTt
    const int nconv8 = NSLOT * N_NODES * F_DIM / 8;  // convert threads

    // --- CSR build for slots 0..6 (t = 5..11) ---
    zero_i32_kernel<<<(ncnt + 255) / 256, 256, 0, stream>>>(counts, ncnt);
    count_kernel<<<(nedge_thr + 255) / 256, 256, 0, stream>>>(adjs, counts);
    scan_kernel<<<NSLOT, 1024, 0, stream>>>(counts, offsets);
    zero_i32_kernel<<<(ncnt + 255) / 256, 256, 0, stream>>>(counts, ncnt);  // reuse as cursor
    fill_kernel<<<(nedge_thr + 255) / 256, 256, 0, stream>>>(adjs, offsets, counts, esrc);

    wtrans16_kernel<<<(3 * LWT + 255) / 256, 256, 0, stream>>>(conv_w, gate_w, wTt);
    whead_kernel<<<(8 * 4 * 16 * 32 + 255) / 256, 256, 0, stream>>>(lin_w, wH);
    feats2f16_kernel<<<(nconv8 + 255) / 256, 256, 0, stream>>>(feats, x16f);

    // --- graph conv, fp16 gathers with slot->XCD affinity (8*2500 blocks) ---
    ax16_kernel<<<8 * (N_NODES / 4), 256, 0, stream>>>(x16f, x16p, offsets, esrc);
    ax16_kernel<<<8 * (N_NODES / 4), 256, 0, stream>>>(x16p, x16a, offsets, esrc);

    // --- gated TCN layers (fp16 MFMA GEMMs) ---
    const int M0 = 5 * N_NODES;   // out slots 2..6, reads 0..6
    conv_gemm_f16_kernel<<<dim3((M0 + CG_BM - 1) / CG_BM, 4), 256, 0, stream>>>(
        x16a, x16b, wTt, conv_b, gate_b, M0, 0, 2);
    const int M1 = 3 * N_NODES;   // out slots 4..6, reads 2..6
    conv_gemm_f16_kernel<<<dim3((M1 + CG_BM - 1) / CG_BM, 4), 256, 0, stream>>>(
        x16b, x16a, wTt + LWT, conv_b + 256, gate_b + 256, M1, 2, 4);
    const int M2 = 1 * N_NODES;   // out slot 6, reads 4..6
    conv_gemm_f16_kernel<<<dim3((M2 + CG_BM - 1) / CG_BM, 4), 256, 0, stream>>>(
        x16a, x16b, wTt + 2 * LWT, conv_b + 512, gate_b + 512, M2, 4, 6);

    // --- head: MFMA linear + in-register log_softmax on slot 6 ---
    head_mfma_kernel<<<(N_NODES + 63) / 64, 256, 0, stream>>>(
        x16b + (size_t)6 * N_NODES * F_DIM, wH, lin_b, out);
}